// Round 3
// baseline (4558.434 us; speedup 1.0000x reference)
//
#include <hip/hip_runtime.h>
#include <hip/hip_bf16.h>
#include <stdint.h>

#define BB 4
#define TT 512
#define NN 4     // heads-inner
#define HH 8     // H
#define DD 64    // D
#define EE 256   // N*D
#define ROWS 2048 // NN*HH*DD, elems per (b,t)

__device__ __forceinline__ float bf2f(unsigned short u) {
    union { unsigned int i; float f; } v;
    v.i = ((unsigned int)u) << 16;
    return v.f;
}
__device__ __forceinline__ unsigned short f2bf(float f) {
    unsigned int x = __float_as_uint(f);
    unsigned int r = (x + 0x7FFFu + ((x >> 16) & 1u)) >> 16;
    return (unsigned short)r;
}
__device__ __forceinline__ float ldv(const void* p, size_t i, bool f32) {
    return f32 ? ((const float*)p)[i] : bf2f(((const unsigned short*)p)[i]);
}
__device__ __forceinline__ void stv(void* p, size_t i, bool f32, float val) {
    if (f32) ((float*)p)[i] = val;
    else     ((unsigned short*)p)[i] = f2bf(val);
}

// One block per (b,h). 1024 threads. No global scratch used at all.
__global__ __launch_bounds__(1024)
void fused_probattn(const void* __restrict__ qp, const void* __restrict__ kp,
                    const void* __restrict__ vp, const int* __restrict__ idx,
                    void* __restrict__ out, int U) {
    __shared__ float vmean[EE];
    __shared__ float M[TT];
    __shared__ float sc[TT];
    __shared__ float qs[EE];
    __shared__ float red[64];
    __shared__ int   Mtop[64];
    __shared__ int   s_f32;

    const int bh = blockIdx.x;
    const int b = bh >> 3, h = bh & 7;
    const int tid = threadIdx.x;
    const int wave = tid >> 6, lane = tid & 63;

    // ---- dtype probe: bf16 Gaussian => max|x| < ~6; fp32-as-bf16 => huge/NaN ----
    if (tid == 0) s_f32 = 0;
    __syncthreads();
    {
        int bad = 0;
        for (int i = tid; i < 4096; i += 1024) {
            float val = bf2f(((const unsigned short*)qp)[i]);
            if (!(fabsf(val) < 100.f)) bad = 1;   // catches big, Inf, NaN
        }
        if (bad) s_f32 = 1;
    }
    __syncthreads();
    const bool f32 = (s_f32 != 0);

    // ---- phase 1: vmean[e] = mean_t V[b,h,t,e] ----
    if (tid < EE) {
        int n = tid >> 6, d = tid & 63;
        size_t base = (size_t)b * TT * ROWS + (size_t)(n * HH + h) * DD + d;
        float acc = 0.f;
        for (int t = 0; t < TT; ++t)
            acc += ldv(vp, base + (size_t)t * ROWS, f32);
        vmean[tid] = acc * (1.0f / TT);
    }
    __syncthreads();

    // ---- phase 1b: broadcast vmean into every output row of this (b,h) ----
    for (int i = tid; i < TT * EE; i += 1024) {
        int t = i >> 8, e = i & 255;
        int n = e >> 6, d = e & 63;
        size_t o = ((size_t)(b * TT + t)) * ROWS + (size_t)(n * HH + h) * DD + d;
        stv(out, o, f32, vmean[e]);
    }

    // ---- phase 2: M[t] = max_s q_t.k_idx - mean... (one wave per t, strided) ----
    {
        int e = lane << 2;
        int n = e >> 6, d = e & 63;
        size_t ebase = (size_t)(n * HH + h) * DD + d;
        for (int t = wave; t < TT; t += 16) {
            size_t qoff = ((size_t)(b * TT + t)) * ROWS + ebase;
            float q0 = ldv(qp, qoff,     f32), q1 = ldv(qp, qoff + 1, f32);
            float q2 = ldv(qp, qoff + 2, f32), q3 = ldv(qp, qoff + 3, f32);
            float mx = -3.4e38f, sm = 0.f;
            for (int s = 0; s < U; ++s) {
                int kt = idx[t * U + s] & (TT - 1);   // defensive clamp
                size_t ko = ((size_t)(b * TT + kt)) * ROWS + ebase;
                float dot = q0 * ldv(kp, ko, f32) + q1 * ldv(kp, ko + 1, f32)
                          + q2 * ldv(kp, ko + 2, f32) + q3 * ldv(kp, ko + 3, f32);
                #pragma unroll
                for (int off = 32; off; off >>= 1)
                    dot += __shfl_xor(dot, off, 64);
                mx = fmaxf(mx, dot);
                sm += dot;
            }
            if (lane == 0) M[t] = mx - sm * (1.0f / TT);
        }
    }
    __syncthreads();

    // ---- phase 3: exact top-k by rank (jax tie-break: lower index wins) ----
    if (tid < 64) Mtop[tid] = 0;   // defensive: never OOB even if ranks collide
    __syncthreads();
    if (tid < TT) {
        float mv = M[tid];
        int rank = 0;
        for (int i = 0; i < TT; ++i) {
            float o = M[i];
            rank += (o > mv) || (o == mv && i < tid);
        }
        if (rank < U) Mtop[rank] = tid;
    }
    __syncthreads();

    // ---- phase 4: for each selected row: QK, softmax, PV, store ----
    for (int ui = 0; ui < U; ++ui) {
        int qt = Mtop[ui];
        if (tid < EE) {
            int n = tid >> 6, d = tid & 63;
            qs[tid] = ldv(qp, ((size_t)(b * TT + qt)) * ROWS + (size_t)(n * HH + h) * DD + d, f32);
        }
        __syncthreads();
        if (tid < TT) {
            float acc = 0.f;
            size_t kb = ((size_t)(b * TT + tid)) * ROWS + (size_t)h * DD;
            for (int n = 0; n < NN; ++n) {
                size_t kn = kb + (size_t)n * HH * DD;
                for (int d = 0; d < DD; ++d)
                    acc += qs[n * 64 + d] * ldv(kp, kn + d, f32);
            }
            sc[tid] = acc * 0.125f;   // 1/sqrt(64)
        }
        __syncthreads();
        // max over 512
        float val = (tid < TT) ? sc[tid] : -3.4e38f;
        #pragma unroll
        for (int off = 32; off; off >>= 1)
            val = fmaxf(val, __shfl_xor(val, off, 64));
        if (lane == 0) red[wave] = val;
        __syncthreads();
        if (tid == 0) {
            float m = red[0];
            for (int w = 1; w < 16; ++w) m = fmaxf(m, red[w]);
            red[32] = m;
        }
        __syncthreads();
        float mx = red[32];
        float ev = 0.f;
        if (tid < TT) { ev = __expf(sc[tid] - mx); sc[tid] = ev; }
        __syncthreads();
        float sv = ev;
        #pragma unroll
        for (int off = 32; off; off >>= 1)
            sv += __shfl_xor(sv, off, 64);
        if (lane == 0) red[wave] = sv;
        __syncthreads();
        if (tid == 0) {
            float s = 0.f;
            for (int w = 0; w < 16; ++w) s += red[w];
            red[32] = s;
        }
        __syncthreads();
        float inv = 1.0f / red[32];
        if (tid < EE) {
            int n = tid >> 6, d = tid & 63;
            size_t vb = (size_t)b * TT * ROWS + (size_t)(n * HH + h) * DD + d;
            float acc = 0.f;
            for (int t = 0; t < TT; ++t)
                acc += sc[t] * ldv(vp, vb + (size_t)t * ROWS, f32);
            stv(out, ((size_t)(b * TT + qt)) * ROWS + (size_t)(n * HH + h) * DD + d,
                f32, acc * inv);
        }
        __syncthreads();
    }
}

extern "C" void kernel_launch(void* const* d_in, const int* in_sizes, int n_in,
                              void* d_out, int out_size, void* d_ws, size_t ws_size,
                              hipStream_t stream) {
    const void* q = d_in[0];
    const void* k = d_in[1];
    const void* v = d_in[2];
    const int* idx = (const int*)d_in[3];
    int U = in_sizes[3] / TT;   // 35

    fused_probattn<<<BB * HH, 1024, 0, stream>>>(q, k, v, idx, d_out, U);
}

// Round 4
// 280.528 us; speedup vs baseline: 16.2495x; 16.2495x over previous
//
#include <hip/hip_runtime.h>
#include <stdint.h>

#define BB 4
#define TT 512
#define NN 4      // heads-inner
#define HH 8      // H
#define DD 64     // D
#define EE 256    // N*D
#define ROWS 2048 // NN*HH*DD floats per (b,t)

// ---------------- fast path (uses 128 KB of d_ws) ----------------

// Stage 1: vmean[bh][e] = mean_t V[b,h,t,e]. Grid: 32 blocks x 1024 thr.
// thread = (chunk<<8)|e, chunk in [0,4): each sums 128 t's, LDS-reduce 4.
__global__ __launch_bounds__(1024)
void vmean_kernel(const float* __restrict__ v, float* __restrict__ vmean) {
    __shared__ float part[4][EE];
    int bh = blockIdx.x;
    int b = bh >> 3, h = bh & 7;
    int e = threadIdx.x & 255;
    int chunk = threadIdx.x >> 8;
    int n = e >> 6, d = e & 63;
    size_t base = (size_t)b * TT * ROWS + (size_t)(n * HH + h) * DD + d;
    float acc = 0.f;
    int t0 = chunk * 128;
    for (int t = t0; t < t0 + 128; ++t)
        acc += v[base + (size_t)t * ROWS];
    part[chunk][e] = acc;
    __syncthreads();
    if (threadIdx.x < EE)
        vmean[bh * EE + threadIdx.x] =
            (part[0][threadIdx.x] + part[1][threadIdx.x] +
             part[2][threadIdx.x] + part[3][threadIdx.x]) * (1.0f / TT);
}

// Stage 2: broadcast vmean into the whole output. float4 stores, coalesced.
// Grid: 4096 blocks x 256 thr.
__global__ void fill_kernel(const float* __restrict__ vmean,
                            float* __restrict__ out) {
    size_t tid4 = ((size_t)blockIdx.x * 256 + threadIdx.x) << 2;
    int d = tid4 & 63;
    size_t rest = tid4 >> 6;
    int h = rest & 7;  rest >>= 3;
    int n = rest & 3;  rest >>= 2;
    int b = (int)(rest >> 9);      // t dropped: vmean is t-independent
    int e = (n << 6) + d;
    int bh = (b << 3) + h;
    float4 val = *(const float4*)(vmean + (size_t)bh * EE + e);
    *(float4*)(out + tid4) = val;
}

// Stage 3: M[bh*T+t] = max_s dot(Q_t, K_idx) - sum_s/T.
// Grid: 4096 blocks x 256 thr (4 waves, one query row per wave).
__global__ void m_kernel(const float* __restrict__ q,
                         const float* __restrict__ k,
                         const int* __restrict__ idx,
                         float* __restrict__ M, int U) {
    int wave = threadIdx.x >> 6, lane = threadIdx.x & 63;
    int r = (blockIdx.x << 2) + wave;     // bh*512 + t
    int t = r & (TT - 1);
    int bh = r >> 9;
    int b = bh >> 3, h = bh & 7;
    int e = lane << 2;
    int n = e >> 6, d = e & 63;
    size_t ebase = (size_t)(n * HH + h) * DD + d;
    float4 qv = *(const float4*)(q + ((size_t)(b * TT + t)) * ROWS + ebase);
    float mx = -3.4e38f, sm = 0.f;
    for (int s = 0; s < U; ++s) {
        int kt = idx[t * U + s] & (TT - 1);
        float4 kv = *(const float4*)(k + ((size_t)(b * TT + kt)) * ROWS + ebase);
        float dot = qv.x * kv.x + qv.y * kv.y + qv.z * kv.z + qv.w * kv.w;
        #pragma unroll
        for (int off = 32; off; off >>= 1)
            dot += __shfl_xor(dot, off, 64);
        mx = fmaxf(mx, dot);
        sm += dot;
    }
    if (lane == 0) M[r] = mx - sm * (1.0f / TT);
}

// Stage 4: exact top-k via rank (jax tie-break: lower index wins).
// Grid: 32 blocks x 512 thr.
__global__ void topk_kernel(const float* __restrict__ M,
                            int* __restrict__ Mtop, int U) {
    __shared__ float sM[TT];
    int bh = blockIdx.x;
    int t = threadIdx.x;
    sM[t] = M[bh * TT + t];
    if (t < 64) Mtop[bh * 64 + t] = 0;   // defensive init (Mtop padded to 64)
    __syncthreads();
    float mv = sM[t];
    int rank = 0;
    for (int i = 0; i < TT; ++i) {
        float o = sM[i];
        rank += (o > mv) || (o == mv && i < t);
    }
    if (rank < U) Mtop[bh * 64 + rank] = t;
}

// Stage 5: softmax-attention row for each selected query, written directly
// into d_out (fill_kernel already ran; rows are distinct per (b,h)).
// Grid: B*H*U blocks x 256 thr.
__global__ void update_kernel(const float* __restrict__ q,
                              const float* __restrict__ k,
                              const float* __restrict__ v,
                              const int* __restrict__ Mtop,
                              float* __restrict__ out, int U) {
    __shared__ float qs[EE];
    __shared__ float sc[TT];
    __shared__ float red[256];
    int blk = blockIdx.x;            // bh*U + ui
    int ui = blk % U;
    int bh = blk / U;
    int b = bh >> 3, h = bh & 7;
    int tid = threadIdx.x;
    int qt = Mtop[bh * 64 + ui] & (TT - 1);
    {
        int n = tid >> 6, d = tid & 63;
        qs[tid] = q[((size_t)(b * TT + qt)) * ROWS + (size_t)(n * HH + h) * DD + d];
    }
    __syncthreads();
    // scores for t = tid and t = tid + 256
    #pragma unroll
    for (int rep = 0; rep < 2; ++rep) {
        int t = tid + rep * 256;
        size_t kb = ((size_t)(b * TT + t)) * ROWS + (size_t)h * DD;
        float acc = 0.f;
        #pragma unroll
        for (int n = 0; n < NN; ++n) {
            const float* kn = k + kb + (size_t)n * HH * DD;
            #pragma unroll 4
            for (int d4 = 0; d4 < DD; d4 += 4) {
                float4 kv = *(const float4*)(kn + d4);
                int e = n * 64 + d4;
                acc += qs[e] * kv.x + qs[e + 1] * kv.y
                     + qs[e + 2] * kv.z + qs[e + 3] * kv.w;
            }
        }
        sc[t] = acc * 0.125f;        // 1/sqrt(64)
    }
    __syncthreads();
    // softmax over 512
    red[tid] = fmaxf(sc[tid], sc[tid + 256]);
    __syncthreads();
    for (int s = 128; s > 0; s >>= 1) {
        if (tid < s) red[tid] = fmaxf(red[tid], red[tid + s]);
        __syncthreads();
    }
    float mx = red[0];
    __syncthreads();
    float e0 = __expf(sc[tid] - mx);
    float e1 = __expf(sc[tid + 256] - mx);
    sc[tid] = e0;
    sc[tid + 256] = e1;
    red[tid] = e0 + e1;
    __syncthreads();
    for (int s = 128; s > 0; s >>= 1) {
        if (tid < s) red[tid] += red[tid + s];
        __syncthreads();
    }
    float inv = 1.0f / red[0];
    __syncthreads();
    // PV: each thread owns one e; write straight to out[b, qt, n, h, d]
    {
        int n = tid >> 6, d = tid & 63;
        size_t vb = (size_t)b * TT * ROWS + (size_t)(n * HH + h) * DD + d;
        float acc = 0.f;
        for (int t = 0; t < TT; ++t)
            acc += sc[t] * v[vb + (size_t)t * ROWS];
        out[((size_t)(b * TT + qt)) * ROWS + (size_t)(n * HH + h) * DD + d] = acc * inv;
    }
}

// ---------------- fallback (no d_ws): round-3 fused kernel, fp32 ----------------
__global__ __launch_bounds__(1024)
void fused_probattn(const float* __restrict__ qp, const float* __restrict__ kp,
                    const float* __restrict__ vp, const int* __restrict__ idx,
                    float* __restrict__ out, int U) {
    __shared__ float vmean[EE];
    __shared__ float M[TT];
    __shared__ float sc[TT];
    __shared__ float qs[EE];
    __shared__ float red[64];
    __shared__ int   Mtop[64];
    const int bh = blockIdx.x;
    const int b = bh >> 3, h = bh & 7;
    const int tid = threadIdx.x;
    const int wave = tid >> 6, lane = tid & 63;
    if (tid < EE) {
        int n = tid >> 6, d = tid & 63;
        size_t base = (size_t)b * TT * ROWS + (size_t)(n * HH + h) * DD + d;
        float acc = 0.f;
        for (int t = 0; t < TT; ++t) acc += vp[base + (size_t)t * ROWS];
        vmean[tid] = acc * (1.0f / TT);
    }
    __syncthreads();
    for (int i = tid; i < TT * EE; i += 1024) {
        int t = i >> 8, e = i & 255;
        int n = e >> 6, d = e & 63;
        out[((size_t)(b * TT + t)) * ROWS + (size_t)(n * HH + h) * DD + d] = vmean[e];
    }
    {
        int e = lane << 2;
        int n = e >> 6, d = e & 63;
        size_t ebase = (size_t)(n * HH + h) * DD + d;
        for (int t = wave; t < TT; t += 16) {
            float4 qv = *(const float4*)(qp + ((size_t)(b * TT + t)) * ROWS + ebase);
            float mx = -3.4e38f, sm = 0.f;
            for (int s = 0; s < U; ++s) {
                int kt = idx[t * U + s] & (TT - 1);
                float4 kv = *(const float4*)(kp + ((size_t)(b * TT + kt)) * ROWS + ebase);
                float dot = qv.x * kv.x + qv.y * kv.y + qv.z * kv.z + qv.w * kv.w;
                #pragma unroll
                for (int off = 32; off; off >>= 1) dot += __shfl_xor(dot, off, 64);
                mx = fmaxf(mx, dot);
                sm += dot;
            }
            if (lane == 0) M[t] = mx - sm * (1.0f / TT);
        }
    }
    __syncthreads();
    if (tid < 64) Mtop[tid] = 0;
    __syncthreads();
    if (tid < TT) {
        float mv = M[tid];
        int rank = 0;
        for (int i = 0; i < TT; ++i) {
            float o = M[i];
            rank += (o > mv) || (o == mv && i < tid);
        }
        if (rank < U) Mtop[rank] = tid;
    }
    __syncthreads();
    for (int ui = 0; ui < U; ++ui) {
        int qt = Mtop[ui];
        if (tid < EE) {
            int n = tid >> 6, d = tid & 63;
            qs[tid] = qp[((size_t)(b * TT + qt)) * ROWS + (size_t)(n * HH + h) * DD + d];
        }
        __syncthreads();
        if (tid < TT) {
            float acc = 0.f;
            size_t kb = ((size_t)(b * TT + tid)) * ROWS + (size_t)h * DD;
            for (int n = 0; n < NN; ++n) {
                const float* kn = kp + kb + (size_t)n * HH * DD;
                for (int d = 0; d < DD; ++d) acc += qs[n * 64 + d] * kn[d];
            }
            sc[tid] = acc * 0.125f;
        }
        __syncthreads();
        float val = (tid < TT) ? sc[tid] : -3.4e38f;
        #pragma unroll
        for (int off = 32; off; off >>= 1) val = fmaxf(val, __shfl_xor(val, off, 64));
        if (lane == 0) red[wave] = val;
        __syncthreads();
        if (tid == 0) {
            float m = red[0];
            for (int w = 1; w < 16; ++w) m = fmaxf(m, red[w]);
            red[32] = m;
        }
        __syncthreads();
        float mx = red[32];
        float ev = 0.f;
        if (tid < TT) { ev = __expf(sc[tid] - mx); sc[tid] = ev; }
        __syncthreads();
        float sv = ev;
        #pragma unroll
        for (int off = 32; off; off >>= 1) sv += __shfl_xor(sv, off, 64);
        if (lane == 0) red[wave] = sv;
        __syncthreads();
        if (tid == 0) {
            float s = 0.f;
            for (int w = 0; w < 16; ++w) s += red[w];
            red[32] = s;
        }
        __syncthreads();
        float inv = 1.0f / red[32];
        if (tid < EE) {
            int n = tid >> 6, d = tid & 63;
            size_t vb = (size_t)b * TT * ROWS + (size_t)(n * HH + h) * DD + d;
            float acc = 0.f;
            for (int t = 0; t < TT; ++t) acc += sc[t] * vp[vb + (size_t)t * ROWS];
            out[((size_t)(b * TT + qt)) * ROWS + (size_t)(n * HH + h) * DD + d] = acc * inv;
        }
        __syncthreads();
    }
}

extern "C" void kernel_launch(void* const* d_in, const int* in_sizes, int n_in,
                              void* d_out, int out_size, void* d_ws, size_t ws_size,
                              hipStream_t stream) {
    const float* q = (const float*)d_in[0];
    const float* k = (const float*)d_in[1];
    const float* v = (const float*)d_in[2];
    const int* idx = (const int*)d_in[3];
    float* out = (float*)d_out;
    int U = in_sizes[3] / TT;        // 35

    const size_t NEED = 160 * 1024;
    if (ws_size >= NEED) {
        char* ws = (char*)d_ws;
        float* M     = (float*)(ws);                  // 32*512 floats = 64 KB
        int*   Mtop  = (int*)  (ws + 64 * 1024);      // 32*64 ints    =  8 KB
        float* vmean = (float*)(ws + 96 * 1024);      // 32*256 floats = 32 KB

        vmean_kernel<<<BB * HH, 1024, 0, stream>>>(v, vmean);
        fill_kernel<<<4096, 256, 0, stream>>>(vmean, out);
        m_kernel<<<BB * HH * TT / 4, 256, 0, stream>>>(q, k, idx, M, U);
        topk_kernel<<<BB * HH, TT, 0, stream>>>(M, Mtop, U);
        update_kernel<<<BB * HH * U, 256, 0, stream>>>(q, k, v, Mtop, out, U);
    } else {
        fused_probattn<<<BB * HH, 1024, 0, stream>>>(q, k, v, idx, out, U);
    }
}

// Round 5
// 194.999 us; speedup vs baseline: 23.3767x; 1.4386x over previous
//
#include <hip/hip_runtime.h>
#include <stdint.h>

#define BB 4
#define TT 512
#define NN 4      // heads-inner
#define HH 8      // H
#define DD 64     // D
#define EE 256    // N*D
#define ROWS 2048 // NN*HH*DD floats per (b,t)
#define UPAD 36   // padded u-count (U=35)
#define NCH 8     // K/V chunks
#define CH 64     // rows per chunk

// ---------------- shared small kernels ----------------

// vmean[bh][e] = mean_t V[b,h,t,e]. Grid: 32 x 1024.
__global__ __launch_bounds__(1024)
void vmean_kernel(const float* __restrict__ v, float* __restrict__ vmean) {
    __shared__ float part[4][EE];
    int bh = blockIdx.x;
    int b = bh >> 3, h = bh & 7;
    int e = threadIdx.x & 255;
    int chunk = threadIdx.x >> 8;
    int n = e >> 6, d = e & 63;
    size_t base = (size_t)b * TT * ROWS + (size_t)(n * HH + h) * DD + d;
    float acc = 0.f;
    int t0 = chunk * 128;
    for (int t = t0; t < t0 + 128; ++t)
        acc += v[base + (size_t)t * ROWS];
    part[chunk][e] = acc;
    __syncthreads();
    if (threadIdx.x < EE)
        vmean[bh * EE + threadIdx.x] =
            (part[0][threadIdx.x] + part[1][threadIdx.x] +
             part[2][threadIdx.x] + part[3][threadIdx.x]) * (1.0f / TT);
}

// broadcast vmean to whole output. Grid: 4096 x 256.
__global__ void fill_kernel(const float* __restrict__ vmean,
                            float* __restrict__ out) {
    size_t tid4 = ((size_t)blockIdx.x * 256 + threadIdx.x) << 2;
    int d = tid4 & 63;
    size_t rest = tid4 >> 6;
    int h = rest & 7;  rest >>= 3;
    int n = rest & 3;  rest >>= 2;
    int b = (int)(rest >> 9);
    int e = (n << 6) + d;
    int bh = (b << 3) + h;
    float4 val = *(const float4*)(vmean + (size_t)bh * EE + e);
    *(float4*)(out + tid4) = val;
}

// M[bh*T+t] = max_s dot(Q_t,K_idx) - sum_s/T. Grid: 4096 x 256.
// One wave per t; lanes in 4 groups of 16 handle 4 samples at once
// (each lane owns 16 e's -> only 4-level intra-group reduce).
__global__ void m_kernel(const float* __restrict__ q,
                         const float* __restrict__ k,
                         const int* __restrict__ idx,
                         float* __restrict__ M, int U) {
    int wave = threadIdx.x >> 6, lane = threadIdx.x & 63;
    int r = (blockIdx.x << 2) + wave;     // bh*512 + t
    int t = r & (TT - 1);
    int bh = r >> 9;
    int b = bh >> 3, h = bh & 7;
    int g = lane >> 4, x = lane & 15;     // group, e-slot
    // lane's e-range: e = 16x + 4j, j=0..3 ; col = ((e>>6)*8+h)*64 + (e&63)
    int n = x >> 2;
    int dbase = ((x & 3) << 4);           // (16x)&63
    size_t colbase = (size_t)(n * HH + h) * DD + dbase;
    size_t qrow = ((size_t)(b * TT + t)) * ROWS + colbase;
    float4 qv0 = *(const float4*)(q + qrow);
    float4 qv1 = *(const float4*)(q + qrow + 4);
    float4 qv2 = *(const float4*)(q + qrow + 8);
    float4 qv3 = *(const float4*)(q + qrow + 12);
    float mx = -3.4e38f, sm = 0.f;
    int NB = (U + 3) >> 2;
    for (int bs = 0; bs < NB; ++bs) {
        int s = (bs << 2) + g;
        int valid = s < U;
        int sc = valid ? s : (U - 1);
        int kt = idx[t * U + sc] & (TT - 1);
        size_t krow = ((size_t)(b * TT + kt)) * ROWS + colbase;
        float4 kv0 = *(const float4*)(k + krow);
        float4 kv1 = *(const float4*)(k + krow + 4);
        float4 kv2 = *(const float4*)(k + krow + 8);
        float4 kv3 = *(const float4*)(k + krow + 12);
        float dot = qv0.x * kv0.x + qv0.y * kv0.y + qv0.z * kv0.z + qv0.w * kv0.w
                  + qv1.x * kv1.x + qv1.y * kv1.y + qv1.z * kv1.z + qv1.w * kv1.w
                  + qv2.x * kv2.x + qv2.y * kv2.y + qv2.z * kv2.z + qv2.w * kv2.w
                  + qv3.x * kv3.x + qv3.y * kv3.y + qv3.z * kv3.z + qv3.w * kv3.w;
        #pragma unroll
        for (int off = 1; off < 16; off <<= 1)
            dot += __shfl_xor(dot, off, 64);
        if (valid) { mx = fmaxf(mx, dot); sm += dot; }
    }
    // combine the 4 groups
    mx = fmaxf(mx, __shfl_xor(mx, 16, 64));
    mx = fmaxf(mx, __shfl_xor(mx, 32, 64));
    sm += __shfl_xor(sm, 16, 64);
    sm += __shfl_xor(sm, 32, 64);
    if (lane == 0) M[r] = mx - sm * (1.0f / TT);
}

// exact top-k via rank. Grid: 32 x 512.
__global__ void topk_kernel(const float* __restrict__ M,
                            int* __restrict__ Mtop, int U) {
    __shared__ float sM[TT];
    int bh = blockIdx.x;
    int t = threadIdx.x;
    sM[t] = M[bh * TT + t];
    if (t < 64) Mtop[bh * 64 + t] = 0;
    __syncthreads();
    float mv = sM[t];
    int rank = 0;
    for (int i = 0; i < TT; ++i) {
        float o = sM[i];
        rank += (o > mv) || (o == mv && i < t);
    }
    if (rank < U) Mtop[bh * 64 + rank] = t;
}

// ---------------- flash-chunked attention (fast path) ----------------
// Grid: 32 bh x 8 chunks = 256 blocks x 256 thr.
// LDS: qs[36][130] + B[64][132] (K stride 129 / V stride 132) + S[36][68] ~62 KB
__global__ __launch_bounds__(256)
void attn_partial(const float* __restrict__ q, const float* __restrict__ k,
                  const float* __restrict__ v, const int* __restrict__ Mtop,
                  float* __restrict__ Opart, float* __restrict__ ml, int U) {
    __shared__ float qs[UPAD * 130];
    __shared__ float Bs[CH * 132];
    __shared__ float S[UPAD * 68];

    int bx = blockIdx.x;
    int bh = bx >> 3, ch = bx & 7;
    int b = bh >> 3, h = bh & 7;
    int tid = threadIdx.x;
    int wv = tid >> 6, l = tid & 63;

    float acc[4][4];
    #pragma unroll
    for (int i = 0; i < 4; ++i)
        #pragma unroll
        for (int j = 0; j < 4; ++j) acc[i][j] = 0.f;

    // ---- S = Qr * K^T over two e-halves ----
    for (int h2 = 0; h2 < 2; ++h2) {
        int eb = h2 * 128;
        // stage Q half: rows u = wv, wv+4, ...
        for (int u = wv; u < UPAD; u += 4) {
            int uu = (u < U) ? u : (U - 1);
            int qt = Mtop[bh * 64 + uu] & (TT - 1);
            size_t rowq = ((size_t)(b * TT + qt)) * ROWS;
            #pragma unroll
            for (int j = 0; j < 2; ++j) {
                int e = eb + l + 64 * j;
                qs[u * 130 + l + 64 * j] = q[rowq + (size_t)((e >> 6) * HH + h) * DD + (e & 63)];
            }
        }
        // stage K half: rows r = wv, wv+4, ...
        for (int r = wv; r < CH; r += 4) {
            size_t rowk = ((size_t)(b * TT + ch * CH + r)) * ROWS;
            #pragma unroll
            for (int j = 0; j < 2; ++j) {
                int e = eb + l + 64 * j;
                Bs[r * 129 + l + 64 * j] = k[rowk + (size_t)((e >> 6) * HH + h) * DD + (e & 63)];
            }
        }
        __syncthreads();
        if (tid < 144) {
            int ug = tid >> 4, tg = tid & 15;
            int u0 = ug << 2, t0 = tg << 2;
            for (int e = 0; e < 128; ++e) {
                float kx0 = Bs[(t0 + 0) * 129 + e];
                float kx1 = Bs[(t0 + 1) * 129 + e];
                float kx2 = Bs[(t0 + 2) * 129 + e];
                float kx3 = Bs[(t0 + 3) * 129 + e];
                #pragma unroll
                for (int i = 0; i < 4; ++i) {
                    float qv = qs[(u0 + i) * 130 + e];
                    acc[i][0] += qv * kx0;
                    acc[i][1] += qv * kx1;
                    acc[i][2] += qv * kx2;
                    acc[i][3] += qv * kx3;
                }
            }
        }
        __syncthreads();
    }
    if (tid < 144) {
        int ug = tid >> 4, tg = tid & 15;
        int u0 = ug << 2, t0 = tg << 2;
        #pragma unroll
        for (int i = 0; i < 4; ++i)
            #pragma unroll
            for (int j = 0; j < 4; ++j)
                S[(u0 + i) * 68 + t0 + j] = acc[i][j] * 0.125f;
    }
    __syncthreads();

    // ---- chunk softmax: per u row, m/l over the 64 t's; overwrite S with P ----
    if (tid < UPAD) {
        float m = -3.4e38f;
        for (int t = 0; t < CH; ++t) m = fmaxf(m, S[tid * 68 + t]);
        float lsum = 0.f;
        for (int t = 0; t < CH; ++t) {
            float p = __expf(S[tid * 68 + t] - m);
            S[tid * 68 + t] = p;
            lsum += p;
        }
        size_t mli = ((size_t)(bh * NCH + ch) * UPAD + tid) * 2;
        ml[mli] = m;
        ml[mli + 1] = lsum;
    }
    __syncthreads();

    // ---- O_part = P * V over two e-halves ----
    int ugp = tid >> 5, el = tid & 31;   // 8 u-groups of 5, 32 e-float4 slots
    int u0p = ugp * 5;
    for (int vh = 0; vh < 2; ++vh) {
        // stage V half into Bs (stride 132)
        for (int r = wv; r < CH; r += 4) {
            size_t rowv = ((size_t)(b * TT + ch * CH + r)) * ROWS;
            #pragma unroll
            for (int j = 0; j < 2; ++j) {
                int e = vh * 128 + l + 64 * j;
                Bs[r * 132 + l + 64 * j] = v[rowv + (size_t)((e >> 6) * HH + h) * DD + (e & 63)];
            }
        }
        __syncthreads();
        float4 o[5];
        #pragma unroll
        for (int i = 0; i < 5; ++i) o[i] = make_float4(0.f, 0.f, 0.f, 0.f);
        for (int t = 0; t < CH; ++t) {
            float4 v4 = *(const float4*)&Bs[t * 132 + 4 * el];
            #pragma unroll
            for (int i = 0; i < 5; ++i) {
                int uc = u0p + i; if (uc > 35) uc = 35;
                float p = S[uc * 68 + t];
                o[i].x += p * v4.x; o[i].y += p * v4.y;
                o[i].z += p * v4.z; o[i].w += p * v4.w;
            }
        }
        #pragma unroll
        for (int i = 0; i < 5; ++i) {
            int u = u0p + i;
            if (u < UPAD)
                *(float4*)&Opart[((size_t)(bh * NCH + ch) * UPAD + u) * EE + vh * 128 + 4 * el] = o[i];
        }
        __syncthreads();
    }
}

// merge chunk partials, write selected rows into out. Grid: 32*U x 64.
__global__ void combine_kernel(const float* __restrict__ Opart,
                               const float* __restrict__ ml,
                               const int* __restrict__ Mtop,
                               float* __restrict__ out, int U) {
    int bx = blockIdx.x;
    int bh = bx / U, ui = bx % U;
    int b = bh >> 3, h = bh & 7;
    int el = threadIdx.x;                // 0..63, float4 each
    float mc[NCH], lc[NCH];
    float gm = -3.4e38f;
    #pragma unroll
    for (int c = 0; c < NCH; ++c) {
        size_t mli = ((size_t)(bh * NCH + c) * UPAD + ui) * 2;
        mc[c] = ml[mli]; lc[c] = ml[mli + 1];
        gm = fmaxf(gm, mc[c]);
    }
    float L = 0.f;
    float fc[NCH];
    #pragma unroll
    for (int c = 0; c < NCH; ++c) { fc[c] = __expf(mc[c] - gm); L += lc[c] * fc[c]; }
    float inv = 1.0f / L;
    float4 a = make_float4(0.f, 0.f, 0.f, 0.f);
    #pragma unroll
    for (int c = 0; c < NCH; ++c) {
        float4 o = *(const float4*)&Opart[((size_t)(bh * NCH + c) * UPAD + ui) * EE + 4 * el];
        a.x += fc[c] * o.x; a.y += fc[c] * o.y;
        a.z += fc[c] * o.z; a.w += fc[c] * o.w;
    }
    int qt = Mtop[bh * 64 + ui] & (TT - 1);
    int e0 = 4 * el, n = el >> 4;
    size_t ooff = ((size_t)(b * TT + qt)) * ROWS + (size_t)(n * HH + h) * DD + (e0 & 63);
    a.x *= inv; a.y *= inv; a.z *= inv; a.w *= inv;
    *(float4*)(out + ooff) = a;
}

// ---------------- mid path: round-4 update kernel (ws >= 160 KB) ----------------
__global__ void update_kernel(const float* __restrict__ q,
                              const float* __restrict__ k,
                              const float* __restrict__ v,
                              const int* __restrict__ Mtop,
                              float* __restrict__ out, int U) {
    __shared__ float qs[EE];
    __shared__ float sc[TT];
    __shared__ float red[256];
    int blk = blockIdx.x;
    int ui = blk % U;
    int bh = blk / U;
    int b = bh >> 3, h = bh & 7;
    int tid = threadIdx.x;
    int qt = Mtop[bh * 64 + ui] & (TT - 1);
    {
        int n = tid >> 6, d = tid & 63;
        qs[tid] = q[((size_t)(b * TT + qt)) * ROWS + (size_t)(n * HH + h) * DD + d];
    }
    __syncthreads();
    #pragma unroll
    for (int rep = 0; rep < 2; ++rep) {
        int t = tid + rep * 256;
        size_t kb = ((size_t)(b * TT + t)) * ROWS + (size_t)h * DD;
        float acc = 0.f;
        #pragma unroll
        for (int n = 0; n < NN; ++n) {
            const float* kn = k + kb + (size_t)n * HH * DD;
            #pragma unroll 4
            for (int d4 = 0; d4 < DD; d4 += 4) {
                float4 kv = *(const float4*)(kn + d4);
                int e = n * 64 + d4;
                acc += qs[e] * kv.x + qs[e + 1] * kv.y + qs[e + 2] * kv.z + qs[e + 3] * kv.w;
            }
        }
        sc[t] = acc * 0.125f;
    }
    __syncthreads();
    red[tid] = fmaxf(sc[tid], sc[tid + 256]);
    __syncthreads();
    for (int s = 128; s > 0; s >>= 1) {
        if (tid < s) red[tid] = fmaxf(red[tid], red[tid + s]);
        __syncthreads();
    }
    float mx = red[0];
    __syncthreads();
    float e0 = __expf(sc[tid] - mx);
    float e1 = __expf(sc[tid + 256] - mx);
    sc[tid] = e0; sc[tid + 256] = e1;
    red[tid] = e0 + e1;
    __syncthreads();
    for (int s = 128; s > 0; s >>= 1) {
        if (tid < s) red[tid] += red[tid + s];
        __syncthreads();
    }
    float inv = 1.0f / red[0];
    __syncthreads();
    {
        int n = tid >> 6, d = tid & 63;
        size_t vb = (size_t)b * TT * ROWS + (size_t)(n * HH + h) * DD + d;
        float acc = 0.f;
        for (int t = 0; t < TT; ++t)
            acc += sc[t] * v[vb + (size_t)t * ROWS];
        out[((size_t)(b * TT + qt)) * ROWS + (size_t)(n * HH + h) * DD + d] = acc * inv;
    }
}

// ---------------- last-resort fallback (no ws): fused, fp32 ----------------
__global__ __launch_bounds__(1024)
void fused_probattn(const float* __restrict__ qp, const float* __restrict__ kp,
                    const float* __restrict__ vp, const int* __restrict__ idx,
                    float* __restrict__ out, int U) {
    __shared__ float vmean[EE];
    __shared__ float M[TT];
    __shared__ float sc[TT];
    __shared__ float qs[EE];
    __shared__ float red[64];
    __shared__ int   Mtop[64];
    const int bh = blockIdx.x;
    const int b = bh >> 3, h = bh & 7;
    const int tid = threadIdx.x;
    const int wave = tid >> 6, lane = tid & 63;
    if (tid < EE) {
        int n = tid >> 6, d = tid & 63;
        size_t base = (size_t)b * TT * ROWS + (size_t)(n * HH + h) * DD + d;
        float acc = 0.f;
        for (int t = 0; t < TT; ++t) acc += vp[base + (size_t)t * ROWS];
        vmean[tid] = acc * (1.0f / TT);
    }
    __syncthreads();
    for (int i = tid; i < TT * EE; i += 1024) {
        int t = i >> 8, e = i & 255;
        int n = e >> 6, d = e & 63;
        out[((size_t)(b * TT + t)) * ROWS + (size_t)(n * HH + h) * DD + d] = vmean[e];
    }
    {
        int e = lane << 2;
        int n = e >> 6, d = e & 63;
        size_t ebase = (size_t)(n * HH + h) * DD + d;
        for (int t = wave; t < TT; t += 16) {
            float4 qv = *(const float4*)(qp + ((size_t)(b * TT + t)) * ROWS + ebase);
            float mx = -3.4e38f, sm = 0.f;
            for (int s = 0; s < U; ++s) {
                int kt = idx[t * U + s] & (TT - 1);
                float4 kv = *(const float4*)(kp + ((size_t)(b * TT + kt)) * ROWS + ebase);
                float dot = qv.x * kv.x + qv.y * kv.y + qv.z * kv.z + qv.w * kv.w;
                #pragma unroll
                for (int off = 32; off; off >>= 1) dot += __shfl_xor(dot, off, 64);
                mx = fmaxf(mx, dot);
                sm += dot;
            }
            if (lane == 0) M[t] = mx - sm * (1.0f / TT);
        }
    }
    __syncthreads();
    if (tid < 64) Mtop[tid] = 0;
    __syncthreads();
    if (tid < TT) {
        float mv = M[tid];
        int rank = 0;
        for (int i = 0; i < TT; ++i) {
            float o = M[i];
            rank += (o > mv) || (o == mv && i < tid);
        }
        if (rank < U) Mtop[rank] = tid;
    }
    __syncthreads();
    for (int ui = 0; ui < U; ++ui) {
        int qt = Mtop[ui];
        if (tid < EE) {
            int n = tid >> 6, d = tid & 63;
            qs[tid] = qp[((size_t)(b * TT + qt)) * ROWS + (size_t)(n * HH + h) * DD + d];
        }
        __syncthreads();
        if (tid < TT) {
            float acc = 0.f;
            size_t kb = ((size_t)(b * TT + tid)) * ROWS + (size_t)h * DD;
            for (int n = 0; n < NN; ++n) {
                const float* kn = kp + kb + (size_t)n * HH * DD;
                for (int d = 0; d < DD; ++d) acc += qs[n * 64 + d] * kn[d];
            }
            sc[tid] = acc * 0.125f;
        }
        __syncthreads();
        float val = (tid < TT) ? sc[tid] : -3.4e38f;
        #pragma unroll
        for (int off = 32; off; off >>= 1) val = fmaxf(val, __shfl_xor(val, off, 64));
        if (lane == 0) red[wave] = val;
        __syncthreads();
        if (tid == 0) {
            float m = red[0];
            for (int w = 1; w < 16; ++w) m = fmaxf(m, red[w]);
            red[32] = m;
        }
        __syncthreads();
        float mx = red[32];
        float ev = 0.f;
        if (tid < TT) { ev = __expf(sc[tid] - mx); sc[tid] = ev; }
        __syncthreads();
        float sv = ev;
        #pragma unroll
        for (int off = 32; off; off >>= 1) sv += __shfl_xor(sv, off, 64);
        if (lane == 0) red[wave] = sv;
        __syncthreads();
        if (tid == 0) {
            float s = 0.f;
            for (int w = 0; w < 16; ++w) s += red[w];
            red[32] = s;
        }
        __syncthreads();
        float inv = 1.0f / red[32];
        if (tid < EE) {
            int n = tid >> 6, d = tid & 63;
            size_t vb = (size_t)b * TT * ROWS + (size_t)(n * HH + h) * DD + d;
            float acc = 0.f;
            for (int t = 0; t < TT; ++t) acc += sc[t] * vp[vb + (size_t)t * ROWS];
            out[((size_t)(b * TT + qt)) * ROWS + (size_t)(n * HH + h) * DD + d] = acc * inv;
        }
        __syncthreads();
    }
}

extern "C" void kernel_launch(void* const* d_in, const int* in_sizes, int n_in,
                              void* d_out, int out_size, void* d_ws, size_t ws_size,
                              hipStream_t stream) {
    const float* q = (const float*)d_in[0];
    const float* k = (const float*)d_in[1];
    const float* v = (const float*)d_in[2];
    const int* idx = (const int*)d_in[3];
    float* out = (float*)d_out;
    int U = in_sizes[3] / TT;        // 35

    // ws layout (bytes):
    //   M      @ 0        (64 KB)
    //   Mtop   @ 65536    (8 KB)
    //   vmean  @ 98304    (32 KB)
    //   ml     @ 131072   (73.7 KB)  [flash only]
    //   Opart  @ 204800   (9.44 MB)  [flash only]
    const size_t NEED_FLASH = 204800 + (size_t)32 * NCH * UPAD * EE * 4 + 1024;
    const size_t NEED_MID = 160 * 1024;
    char* ws = (char*)d_ws;
    float* M     = (float*)(ws);
    int*   Mtop  = (int*)  (ws + 65536);
    float* vmean = (float*)(ws + 98304);
    float* ml    = (float*)(ws + 131072);
    float* Opart = (float*)(ws + 204800);

    if (ws_size >= NEED_FLASH && U == 35) {
        vmean_kernel<<<BB * HH, 1024, 0, stream>>>(v, vmean);
        fill_kernel<<<4096, 256, 0, stream>>>(vmean, out);
        m_kernel<<<BB * HH * TT / 4, 256, 0, stream>>>(q, k, idx, M, U);
        topk_kernel<<<BB * HH, TT, 0, stream>>>(M, Mtop, U);
        attn_partial<<<BB * HH * NCH, 256, 0, stream>>>(q, k, v, Mtop, Opart, ml, U);
        combine_kernel<<<BB * HH * U, 64, 0, stream>>>(Opart, ml, Mtop, out, U);
    } else if (ws_size >= NEED_MID) {
        vmean_kernel<<<BB * HH, 1024, 0, stream>>>(v, vmean);
        fill_kernel<<<4096, 256, 0, stream>>>(vmean, out);
        m_kernel<<<BB * HH * TT / 4, 256, 0, stream>>>(q, k, idx, M, U);
        topk_kernel<<<BB * HH, TT, 0, stream>>>(M, Mtop, U);
        update_kernel<<<BB * HH * U, 256, 0, stream>>>(q, k, v, Mtop, out, U);
    } else {
        fused_probattn<<<BB * HH, 1024, 0, stream>>>(q, k, v, idx, out, U);
    }
}

// Round 6
// 186.767 us; speedup vs baseline: 24.4071x; 1.0441x over previous
//
#include <hip/hip_runtime.h>
#include <stdint.h>

#define BB 4
#define TT 512
#define NN 4      // heads-inner
#define HH 8      // H
#define DD 64     // D
#define EE 256    // N*D
#define ROWS 2048 // NN*HH*DD floats per (b,t)
#define UPAD 36   // padded u-count (U=35)
#define NCH 8     // K/V chunks
#define CH 64     // rows per chunk

// ---------------- flash-path kernels ----------------

// vmean partials: grid 256 blocks (bh*8+chunk) x 256 thr; each thread sums 64 t.
__global__ void vmean_part_kernel(const float* __restrict__ v,
                                  float* __restrict__ vpart) {
    int blk = blockIdx.x;
    int chunk = blk & 7;
    int bh = blk >> 3;
    int b = bh >> 3, h = bh & 7;
    int e = threadIdx.x;
    int n = e >> 6, d = e & 63;
    size_t base = (size_t)b * TT * ROWS + (size_t)(n * HH + h) * DD + d;
    float acc = 0.f;
    int t0 = chunk * 64;
    for (int t = t0; t < t0 + 64; ++t)
        acc += v[base + (size_t)t * ROWS];
    vpart[blk * EE + e] = acc;
}

// broadcast vmean to whole output. Grid: 4096 x 256.
__global__ void fill_kernel(const float* __restrict__ vmean,
                            float* __restrict__ out) {
    size_t tid4 = ((size_t)blockIdx.x * 256 + threadIdx.x) << 2;
    int d = tid4 & 63;
    size_t rest = tid4 >> 6;
    int h = rest & 7;  rest >>= 3;
    int n = rest & 3;  rest >>= 2;
    int b = (int)(rest >> 9);
    int e = (n << 6) + d;
    int bh = (b << 3) + h;
    float4 val = *(const float4*)(vmean + (size_t)bh * EE + e);
    *(float4*)(out + tid4) = val;
}

// M[bh*T+t] = max_s dot(Q_t,K_idx) - sum_s/T. Grid: 4096 x 256.
// XCD-aware swizzle: blockIdx % 8 -> XCD (round-robin dispatch heuristic);
// each XCD owns 4 (b,h) slices -> per-XCD K working set ~2 MB < 4 MB L2.
__global__ void m_kernel(const float* __restrict__ q,
                         const float* __restrict__ k,
                         const int* __restrict__ idx,
                         float* __restrict__ M, int U) {
    int wave = threadIdx.x >> 6, lane = threadIdx.x & 63;
    int xcd = blockIdx.x & 7;
    int bh = (xcd << 2) | ((blockIdx.x >> 3) & 3);
    int t = ((blockIdx.x >> 5) << 2) + wave;
    int r = (bh << 9) + t;
    int b = bh >> 3, h = bh & 7;
    int g = lane >> 4, x = lane & 15;     // sample-group, e-slot
    int n = x >> 2;
    int dbase = ((x & 3) << 4);
    size_t colbase = (size_t)(n * HH + h) * DD + dbase;
    size_t qrow = ((size_t)(b * TT + t)) * ROWS + colbase;
    float4 qv0 = *(const float4*)(q + qrow);
    float4 qv1 = *(const float4*)(q + qrow + 4);
    float4 qv2 = *(const float4*)(q + qrow + 8);
    float4 qv3 = *(const float4*)(q + qrow + 12);
    float mx = -3.4e38f, sm = 0.f;
    int NB = (U + 3) >> 2;
    for (int bs = 0; bs < NB; ++bs) {
        int s = (bs << 2) + g;
        int valid = s < U;
        int sc = valid ? s : (U - 1);
        int kt = idx[t * U + sc] & (TT - 1);
        size_t krow = ((size_t)(b * TT + kt)) * ROWS + colbase;
        float4 kv0 = *(const float4*)(k + krow);
        float4 kv1 = *(const float4*)(k + krow + 4);
        float4 kv2 = *(const float4*)(k + krow + 8);
        float4 kv3 = *(const float4*)(k + krow + 12);
        float dot = qv0.x * kv0.x + qv0.y * kv0.y + qv0.z * kv0.z + qv0.w * kv0.w
                  + qv1.x * kv1.x + qv1.y * kv1.y + qv1.z * kv1.z + qv1.w * kv1.w
                  + qv2.x * kv2.x + qv2.y * kv2.y + qv2.z * kv2.z + qv2.w * kv2.w
                  + qv3.x * kv3.x + qv3.y * kv3.y + qv3.z * kv3.z + qv3.w * kv3.w;
        #pragma unroll
        for (int off = 1; off < 16; off <<= 1)
            dot += __shfl_xor(dot, off, 64);
        if (valid) { mx = fmaxf(mx, dot); sm += dot; }
    }
    mx = fmaxf(mx, __shfl_xor(mx, 16, 64));
    mx = fmaxf(mx, __shfl_xor(mx, 32, 64));
    sm += __shfl_xor(sm, 16, 64);
    sm += __shfl_xor(sm, 32, 64);
    if (lane == 0) M[r] = mx - sm * (1.0f / TT);
}

// exact top-k via rank + fused vmean final reduce. Grid: 32 x 512.
__global__ void topk_kernel(const float* __restrict__ M,
                            int* __restrict__ Mtop,
                            const float* __restrict__ vpart,
                            float* __restrict__ vmean, int U) {
    __shared__ float sM[TT];
    int bh = blockIdx.x;
    int t = threadIdx.x;
    sM[t] = M[bh * TT + t];
    if (t < 64) Mtop[bh * 64 + t] = 0;
    // fused vmean final: threads 0..255 reduce the 8 chunk partials
    if (t < EE) {
        float acc = 0.f;
        #pragma unroll
        for (int c = 0; c < 8; ++c)
            acc += vpart[(bh * 8 + c) * EE + t];
        vmean[bh * EE + t] = acc * (1.0f / TT);
    }
    __syncthreads();
    float mv = sM[t];
    int rank = 0;
    for (int i = 0; i < TT; ++i) {
        float o = sM[i];
        rank += (o > mv) || (o == mv && i < t);
    }
    if (rank < U) Mtop[bh * 64 + rank] = t;
}

// flash-chunked attention. Grid: 32 bh x 8 chunks = 256 blocks x 256 thr.
__global__ __launch_bounds__(256)
void attn_partial(const float* __restrict__ q, const float* __restrict__ k,
                  const float* __restrict__ v, const int* __restrict__ Mtop,
                  float* __restrict__ Opart, float* __restrict__ ml, int U) {
    __shared__ float qs[UPAD * 130];
    __shared__ float Bs[CH * 132];
    __shared__ float S[UPAD * 68];

    int bx = blockIdx.x;
    int bh = bx >> 3, ch = bx & 7;
    int b = bh >> 3, h = bh & 7;
    int tid = threadIdx.x;
    int wv = tid >> 6, l = tid & 63;

    float acc[4][4];
    #pragma unroll
    for (int i = 0; i < 4; ++i)
        #pragma unroll
        for (int j = 0; j < 4; ++j) acc[i][j] = 0.f;

    for (int h2 = 0; h2 < 2; ++h2) {
        int eb = h2 * 128;
        for (int u = wv; u < UPAD; u += 4) {
            int uu = (u < U) ? u : (U - 1);
            int qt = Mtop[bh * 64 + uu] & (TT - 1);
            size_t rowq = ((size_t)(b * TT + qt)) * ROWS;
            #pragma unroll
            for (int j = 0; j < 2; ++j) {
                int e = eb + l + 64 * j;
                qs[u * 130 + l + 64 * j] = q[rowq + (size_t)((e >> 6) * HH + h) * DD + (e & 63)];
            }
        }
        for (int r = wv; r < CH; r += 4) {
            size_t rowk = ((size_t)(b * TT + ch * CH + r)) * ROWS;
            #pragma unroll
            for (int j = 0; j < 2; ++j) {
                int e = eb + l + 64 * j;
                Bs[r * 129 + l + 64 * j] = k[rowk + (size_t)((e >> 6) * HH + h) * DD + (e & 63)];
            }
        }
        __syncthreads();
        if (tid < 144) {
            int ug = tid >> 4, tg = tid & 15;
            int u0 = ug << 2, t0 = tg << 2;
            for (int e = 0; e < 128; ++e) {
                float kx0 = Bs[(t0 + 0) * 129 + e];
                float kx1 = Bs[(t0 + 1) * 129 + e];
                float kx2 = Bs[(t0 + 2) * 129 + e];
                float kx3 = Bs[(t0 + 3) * 129 + e];
                #pragma unroll
                for (int i = 0; i < 4; ++i) {
                    float qv = qs[(u0 + i) * 130 + e];
                    acc[i][0] += qv * kx0;
                    acc[i][1] += qv * kx1;
                    acc[i][2] += qv * kx2;
                    acc[i][3] += qv * kx3;
                }
            }
        }
        __syncthreads();
    }
    if (tid < 144) {
        int ug = tid >> 4, tg = tid & 15;
        int u0 = ug << 2, t0 = tg << 2;
        #pragma unroll
        for (int i = 0; i < 4; ++i)
            #pragma unroll
            for (int j = 0; j < 4; ++j)
                S[(u0 + i) * 68 + t0 + j] = acc[i][j] * 0.125f;
    }
    __syncthreads();

    if (tid < UPAD) {
        float m = -3.4e38f;
        for (int t = 0; t < CH; ++t) m = fmaxf(m, S[tid * 68 + t]);
        float lsum = 0.f;
        for (int t = 0; t < CH; ++t) {
            float p = __expf(S[tid * 68 + t] - m);
            S[tid * 68 + t] = p;
            lsum += p;
        }
        size_t mli = ((size_t)(bh * NCH + ch) * UPAD + tid) * 2;
        ml[mli] = m;
        ml[mli + 1] = lsum;
    }
    __syncthreads();

    int ugp = tid >> 5, el = tid & 31;
    int u0p = ugp * 5;
    for (int vh = 0; vh < 2; ++vh) {
        for (int r = wv; r < CH; r += 4) {
            size_t rowv = ((size_t)(b * TT + ch * CH + r)) * ROWS;
            #pragma unroll
            for (int j = 0; j < 2; ++j) {
                int e = vh * 128 + l + 64 * j;
                Bs[r * 132 + l + 64 * j] = v[rowv + (size_t)((e >> 6) * HH + h) * DD + (e & 63)];
            }
        }
        __syncthreads();
        float4 o[5];
        #pragma unroll
        for (int i = 0; i < 5; ++i) o[i] = make_float4(0.f, 0.f, 0.f, 0.f);
        for (int t = 0; t < CH; ++t) {
            float4 v4 = *(const float4*)&Bs[t * 132 + 4 * el];
            #pragma unroll
            for (int i = 0; i < 5; ++i) {
                int uc = u0p + i; if (uc > 35) uc = 35;
                float p = S[uc * 68 + t];
                o[i].x += p * v4.x; o[i].y += p * v4.y;
                o[i].z += p * v4.z; o[i].w += p * v4.w;
            }
        }
        #pragma unroll
        for (int i = 0; i < 5; ++i) {
            int u = u0p + i;
            if (u < UPAD)
                *(float4*)&Opart[((size_t)(bh * NCH + ch) * UPAD + u) * EE + vh * 128 + 4 * el] = o[i];
        }
        __syncthreads();
    }
}

// merge chunk partials, write selected rows into out. Grid: 32*U x 64.
__global__ void combine_kernel(const float* __restrict__ Opart,
                               const float* __restrict__ ml,
                               const int* __restrict__ Mtop,
                               float* __restrict__ out, int U) {
    int bx = blockIdx.x;
    int bh = bx / U, ui = bx % U;
    int b = bh >> 3, h = bh & 7;
    int el = threadIdx.x;
    float mc[NCH], lc[NCH];
    float gm = -3.4e38f;
    #pragma unroll
    for (int c = 0; c < NCH; ++c) {
        size_t mli = ((size_t)(bh * NCH + c) * UPAD + ui) * 2;
        mc[c] = ml[mli]; lc[c] = ml[mli + 1];
        gm = fmaxf(gm, mc[c]);
    }
    float L = 0.f;
    float fc[NCH];
    #pragma unroll
    for (int c = 0; c < NCH; ++c) { fc[c] = __expf(mc[c] - gm); L += lc[c] * fc[c]; }
    float inv = 1.0f / L;
    float4 a = make_float4(0.f, 0.f, 0.f, 0.f);
    #pragma unroll
    for (int c = 0; c < NCH; ++c) {
        float4 o = *(const float4*)&Opart[((size_t)(bh * NCH + c) * UPAD + ui) * EE + 4 * el];
        a.x += fc[c] * o.x; a.y += fc[c] * o.y;
        a.z += fc[c] * o.z; a.w += fc[c] * o.w;
    }
    int qt = Mtop[bh * 64 + ui] & (TT - 1);
    int e0 = 4 * el, n = el >> 4;
    size_t ooff = ((size_t)(b * TT + qt)) * ROWS + (size_t)(n * HH + h) * DD + (e0 & 63);
    a.x *= inv; a.y *= inv; a.z *= inv; a.w *= inv;
    *(float4*)(out + ooff) = a;
}

// ---------------- mid-path kernels (ws >= 160 KB only) ----------------

__global__ __launch_bounds__(1024)
void vmean_kernel(const float* __restrict__ v, float* __restrict__ vmean) {
    __shared__ float part[4][EE];
    int bh = blockIdx.x;
    int b = bh >> 3, h = bh & 7;
    int e = threadIdx.x & 255;
    int chunk = threadIdx.x >> 8;
    int n = e >> 6, d = e & 63;
    size_t base = (size_t)b * TT * ROWS + (size_t)(n * HH + h) * DD + d;
    float acc = 0.f;
    int t0 = chunk * 128;
    for (int t = t0; t < t0 + 128; ++t)
        acc += v[base + (size_t)t * ROWS];
    part[chunk][e] = acc;
    __syncthreads();
    if (threadIdx.x < EE)
        vmean[bh * EE + threadIdx.x] =
            (part[0][threadIdx.x] + part[1][threadIdx.x] +
             part[2][threadIdx.x] + part[3][threadIdx.x]) * (1.0f / TT);
}

__global__ void topk_only_kernel(const float* __restrict__ M,
                                 int* __restrict__ Mtop, int U) {
    __shared__ float sM[TT];
    int bh = blockIdx.x;
    int t = threadIdx.x;
    sM[t] = M[bh * TT + t];
    if (t < 64) Mtop[bh * 64 + t] = 0;
    __syncthreads();
    float mv = sM[t];
    int rank = 0;
    for (int i = 0; i < TT; ++i) {
        float o = sM[i];
        rank += (o > mv) || (o == mv && i < t);
    }
    if (rank < U) Mtop[bh * 64 + rank] = t;
}

__global__ void update_kernel(const float* __restrict__ q,
                              const float* __restrict__ k,
                              const float* __restrict__ v,
                              const int* __restrict__ Mtop,
                              float* __restrict__ out, int U) {
    __shared__ float qs[EE];
    __shared__ float sc[TT];
    __shared__ float red[256];
    int blk = blockIdx.x;
    int ui = blk % U;
    int bh = blk / U;
    int b = bh >> 3, h = bh & 7;
    int tid = threadIdx.x;
    int qt = Mtop[bh * 64 + ui] & (TT - 1);
    {
        int n = tid >> 6, d = tid & 63;
        qs[tid] = q[((size_t)(b * TT + qt)) * ROWS + (size_t)(n * HH + h) * DD + d];
    }
    __syncthreads();
    #pragma unroll
    for (int rep = 0; rep < 2; ++rep) {
        int t = tid + rep * 256;
        size_t kb = ((size_t)(b * TT + t)) * ROWS + (size_t)h * DD;
        float acc = 0.f;
        #pragma unroll
        for (int n = 0; n < NN; ++n) {
            const float* kn = k + kb + (size_t)n * HH * DD;
            #pragma unroll 4
            for (int d4 = 0; d4 < DD; d4 += 4) {
                float4 kv = *(const float4*)(kn + d4);
                int e = n * 64 + d4;
                acc += qs[e] * kv.x + qs[e + 1] * kv.y + qs[e + 2] * kv.z + qs[e + 3] * kv.w;
            }
        }
        sc[t] = acc * 0.125f;
    }
    __syncthreads();
    red[tid] = fmaxf(sc[tid], sc[tid + 256]);
    __syncthreads();
    for (int s = 128; s > 0; s >>= 1) {
        if (tid < s) red[tid] = fmaxf(red[tid], red[tid + s]);
        __syncthreads();
    }
    float mx = red[0];
    __syncthreads();
    float e0 = __expf(sc[tid] - mx);
    float e1 = __expf(sc[tid + 256] - mx);
    sc[tid] = e0; sc[tid + 256] = e1;
    red[tid] = e0 + e1;
    __syncthreads();
    for (int s = 128; s > 0; s >>= 1) {
        if (tid < s) red[tid] += red[tid + s];
        __syncthreads();
    }
    float inv = 1.0f / red[0];
    __syncthreads();
    {
        int n = tid >> 6, d = tid & 63;
        size_t vb = (size_t)b * TT * ROWS + (size_t)(n * HH + h) * DD + d;
        float acc = 0.f;
        for (int t = 0; t < TT; ++t)
            acc += sc[t] * v[vb + (size_t)t * ROWS];
        out[((size_t)(b * TT + qt)) * ROWS + (size_t)(n * HH + h) * DD + d] = acc * inv;
    }
}

// ---------------- last-resort fallback (no ws): fused, fp32 ----------------
__global__ __launch_bounds__(1024)
void fused_probattn(const float* __restrict__ qp, const float* __restrict__ kp,
                    const float* __restrict__ vp, const int* __restrict__ idx,
                    float* __restrict__ out, int U) {
    __shared__ float vmean[EE];
    __shared__ float M[TT];
    __shared__ float sc[TT];
    __shared__ float qs[EE];
    __shared__ float red[64];
    __shared__ int   Mtop[64];
    const int bh = blockIdx.x;
    const int b = bh >> 3, h = bh & 7;
    const int tid = threadIdx.x;
    const int wave = tid >> 6, lane = tid & 63;
    if (tid < EE) {
        int n = tid >> 6, d = tid & 63;
        size_t base = (size_t)b * TT * ROWS + (size_t)(n * HH + h) * DD + d;
        float acc = 0.f;
        for (int t = 0; t < TT; ++t) acc += vp[base + (size_t)t * ROWS];
        vmean[tid] = acc * (1.0f / TT);
    }
    __syncthreads();
    for (int i = tid; i < TT * EE; i += 1024) {
        int t = i >> 8, e = i & 255;
        int n = e >> 6, d = e & 63;
        out[((size_t)(b * TT + t)) * ROWS + (size_t)(n * HH + h) * DD + d] = vmean[e];
    }
    {
        int e = lane << 2;
        int n = e >> 6, d = e & 63;
        size_t ebase = (size_t)(n * HH + h) * DD + d;
        for (int t = wave; t < TT; t += 16) {
            float4 qv = *(const float4*)(qp + ((size_t)(b * TT + t)) * ROWS + ebase);
            float mx = -3.4e38f, sm = 0.f;
            for (int s = 0; s < U; ++s) {
                int kt = idx[t * U + s] & (TT - 1);
                float4 kv = *(const float4*)(kp + ((size_t)(b * TT + kt)) * ROWS + ebase);
                float dot = qv.x * kv.x + qv.y * kv.y + qv.z * kv.z + qv.w * kv.w;
                #pragma unroll
                for (int off = 32; off; off >>= 1) dot += __shfl_xor(dot, off, 64);
                mx = fmaxf(mx, dot);
                sm += dot;
            }
            if (lane == 0) M[t] = mx - sm * (1.0f / TT);
        }
    }
    __syncthreads();
    if (tid < 64) Mtop[tid] = 0;
    __syncthreads();
    if (tid < TT) {
        float mv = M[tid];
        int rank = 0;
        for (int i = 0; i < TT; ++i) {
            float o = M[i];
            rank += (o > mv) || (o == mv && i < tid);
        }
        if (rank < U) Mtop[rank] = tid;
    }
    __syncthreads();
    for (int ui = 0; ui < U; ++ui) {
        int qt = Mtop[ui];
        if (tid < EE) {
            int n = tid >> 6, d = tid & 63;
            qs[tid] = qp[((size_t)(b * TT + qt)) * ROWS + (size_t)(n * HH + h) * DD + d];
        }
        __syncthreads();
        if (tid < TT) {
            float acc = 0.f;
            size_t kb = ((size_t)(b * TT + tid)) * ROWS + (size_t)h * DD;
            for (int n = 0; n < NN; ++n) {
                const float* kn = kp + kb + (size_t)n * HH * DD;
                for (int d = 0; d < DD; ++d) acc += qs[n * 64 + d] * kn[d];
            }
            sc[tid] = acc * 0.125f;
        }
        __syncthreads();
        float val = (tid < TT) ? sc[tid] : -3.4e38f;
        #pragma unroll
        for (int off = 32; off; off >>= 1) val = fmaxf(val, __shfl_xor(val, off, 64));
        if (lane == 0) red[wave] = val;
        __syncthreads();
        if (tid == 0) {
            float m = red[0];
            for (int w = 1; w < 16; ++w) m = fmaxf(m, red[w]);
            red[32] = m;
        }
        __syncthreads();
        float mx = red[32];
        float ev = 0.f;
        if (tid < TT) { ev = __expf(sc[tid] - mx); sc[tid] = ev; }
        __syncthreads();
        float sv = ev;
        #pragma unroll
        for (int off = 32; off; off >>= 1) sv += __shfl_xor(sv, off, 64);
        if (lane == 0) red[wave] = sv;
        __syncthreads();
        if (tid == 0) {
            float s = 0.f;
            for (int w = 0; w < 16; ++w) s += red[w];
            red[32] = s;
        }
        __syncthreads();
        float inv = 1.0f / red[32];
        if (tid < EE) {
            int n = tid >> 6, d = tid & 63;
            size_t vb = (size_t)b * TT * ROWS + (size_t)(n * HH + h) * DD + d;
            float acc = 0.f;
            for (int t = 0; t < TT; ++t) acc += sc[t] * vp[vb + (size_t)t * ROWS];
            out[((size_t)(b * TT + qt)) * ROWS + (size_t)(n * HH + h) * DD + d] = acc * inv;
        }
        __syncthreads();
    }
}

extern "C" void kernel_launch(void* const* d_in, const int* in_sizes, int n_in,
                              void* d_out, int out_size, void* d_ws, size_t ws_size,
                              hipStream_t stream) {
    const float* q = (const float*)d_in[0];
    const float* k = (const float*)d_in[1];
    const float* v = (const float*)d_in[2];
    const int* idx = (const int*)d_in[3];
    float* out = (float*)d_out;
    int U = in_sizes[3] / TT;        // 35

    // ws layout (bytes):
    //   M      @ 0        (64 KB)
    //   Mtop   @ 65536    (8 KB)
    //   vmean  @ 98304    (32 KB)
    //   ml     @ 131072   (73.7 KB)  [flash only]
    //   Opart  @ 204800   (9.44 MB)  [flash only]
    //   vpart  @ 204800   (256 KB)   [flash only; aliases Opart — disjoint lifetime:
    //                                 vpart dies at topk, Opart born at attn_partial]
    const size_t NEED_FLASH = 204800 + (size_t)32 * NCH * UPAD * EE * 4 + 1024;
    const size_t NEED_MID = 160 * 1024;
    char* ws = (char*)d_ws;
    float* M     = (float*)(ws);
    int*   Mtop  = (int*)  (ws + 65536);
    float* vmean = (float*)(ws + 98304);
    float* ml    = (float*)(ws + 131072);
    float* Opart = (float*)(ws + 204800);
    float* vpart = (float*)(ws + 204800);

    if (ws_size >= NEED_FLASH && U == 35) {
        vmean_part_kernel<<<BB * HH * 8, 256, 0, stream>>>(v, vpart);
        m_kernel<<<BB * HH * TT / 4, 256, 0, stream>>>(q, k, idx, M, U);
        topk_kernel<<<BB * HH, TT, 0, stream>>>(M, Mtop, vpart, vmean, U);
        fill_kernel<<<4096, 256, 0, stream>>>(vmean, out);
        attn_partial<<<BB * HH * NCH, 256, 0, stream>>>(q, k, v, Mtop, Opart, ml, U);
        combine_kernel<<<BB * HH * U, 64, 0, stream>>>(Opart, ml, Mtop, out, U);
    } else if (ws_size >= NEED_MID) {
        vmean_kernel<<<BB * HH, 1024, 0, stream>>>(v, vmean);
        fill_kernel<<<4096, 256, 0, stream>>>(vmean, out);
        m_kernel<<<BB * HH * TT / 4, 256, 0, stream>>>(q, k, idx, M, U);
        topk_only_kernel<<<BB * HH, TT, 0, stream>>>(M, Mtop, U);
        update_kernel<<<BB * HH * U, 256, 0, stream>>>(q, k, v, Mtop, out, U);
    } else {
        fused_probattn<<<BB * HH, 1024, 0, stream>>>(q, k, v, idx, out, U);
    }
}

// Round 7
// 186.506 us; speedup vs baseline: 24.4412x; 1.0014x over previous
//
#include <hip/hip_runtime.h>
#include <stdint.h>

#define BB 4
#define TT 512
#define NN 4      // heads-inner
#define HH 8      // H
#define DD 64     // D
#define EE 256    // N*D
#define ROWS 2048 // NN*HH*DD floats per (b,t)
#define UPAD 36   // padded u-count (U=35)
#define NCH 8     // K/V chunks
#define CH 64     // rows per chunk

// ---------------- flash-path kernels ----------------

// Fused M-score + vmean partials.
// Blocks 0..4095: M[bh*T+t] with XCD swizzle + LDS idx cache + 2-deep pipeline.
// Blocks 4096..4351: vmean partials (bh*8+chunk).
__global__ __launch_bounds__(256)
void m_vmean_kernel(const float* __restrict__ q, const float* __restrict__ k,
                    const float* __restrict__ v, const int* __restrict__ idx,
                    float* __restrict__ M, float* __restrict__ vpart, int U) {
    if (blockIdx.x >= 4096) {
        int blk = blockIdx.x - 4096;
        int chunk = blk & 7, bh = blk >> 3;
        int b = bh >> 3, h = bh & 7;
        int e = threadIdx.x;
        int n = e >> 6, d = e & 63;
        size_t base = (size_t)b * TT * ROWS + (size_t)(n * HH + h) * DD + d;
        float acc = 0.f;
        int t0 = chunk * 64;
        for (int t = t0; t < t0 + 64; ++t)
            acc += v[base + (size_t)t * ROWS];
        vpart[blk * EE + e] = acc;
        return;
    }
    __shared__ int sidx[4][40];
    int wave = threadIdx.x >> 6, lane = threadIdx.x & 63;
    int xcd = blockIdx.x & 7;
    int bh = (xcd << 2) | ((blockIdx.x >> 3) & 3);
    int t = ((blockIdx.x >> 5) << 2) + wave;
    int b = bh >> 3, h = bh & 7;
    if (lane < U) sidx[wave][lane] = idx[t * U + lane] & (TT - 1);
    int g = lane >> 4, x = lane & 15;     // sample-group, e-slot
    int n = x >> 2;
    int dbase = (x & 3) << 4;
    size_t colbase = (size_t)(n * HH + h) * DD + dbase;
    const float* qr = q + ((size_t)(b * TT + t)) * ROWS + colbase;
    float4 qv0 = *(const float4*)qr;
    float4 qv1 = *(const float4*)(qr + 4);
    float4 qv2 = *(const float4*)(qr + 8);
    float4 qv3 = *(const float4*)(qr + 12);
    float mx = -3.4e38f, sm = 0.f;
    const int NB = (U + 3) >> 2;          // 9
    // prefetch sample-block 0
    int sP = g; if (sP >= U) sP = U - 1;
    const float* kr = k + ((size_t)(b * TT + sidx[wave][sP])) * ROWS + colbase;
    float4 c0 = *(const float4*)kr,       c1 = *(const float4*)(kr + 4),
           c2 = *(const float4*)(kr + 8), c3 = *(const float4*)(kr + 12);
    for (int bs = 0; bs < NB; ++bs) {
        // branchless prefetch of next block (clamped; last iter re-loads a safe row)
        int sn = ((bs + 1) << 2) + g;
        if (sn >= U) sn = U - 1;
        const float* krn = k + ((size_t)(b * TT + sidx[wave][sn])) * ROWS + colbase;
        float4 n0 = *(const float4*)krn,       n1 = *(const float4*)(krn + 4),
               n2 = *(const float4*)(krn + 8), n3 = *(const float4*)(krn + 12);
        float dot = qv0.x * c0.x + qv0.y * c0.y + qv0.z * c0.z + qv0.w * c0.w
                  + qv1.x * c1.x + qv1.y * c1.y + qv1.z * c1.z + qv1.w * c1.w
                  + qv2.x * c2.x + qv2.y * c2.y + qv2.z * c2.z + qv2.w * c2.w
                  + qv3.x * c3.x + qv3.y * c3.y + qv3.z * c3.z + qv3.w * c3.w;
        #pragma unroll
        for (int off = 1; off < 16; off <<= 1)
            dot += __shfl_xor(dot, off, 64);
        int s = (bs << 2) + g;
        if (s < U) { mx = fmaxf(mx, dot); sm += dot; }
        c0 = n0; c1 = n1; c2 = n2; c3 = n3;
    }
    mx = fmaxf(mx, __shfl_xor(mx, 16, 64));
    mx = fmaxf(mx, __shfl_xor(mx, 32, 64));
    sm += __shfl_xor(sm, 16, 64);
    sm += __shfl_xor(sm, 32, 64);
    if (lane == 0) M[(bh << 9) + t] = mx - sm * (1.0f / TT);
}

// exact top-k via rank + fused vmean final reduce. Grid: 32 x 512.
__global__ void topk_kernel(const float* __restrict__ M,
                            int* __restrict__ Mtop,
                            const float* __restrict__ vpart,
                            float* __restrict__ vmean, int U) {
    __shared__ float sM[TT];
    int bh = blockIdx.x;
    int t = threadIdx.x;
    sM[t] = M[bh * TT + t];
    if (t < 64) Mtop[bh * 64 + t] = 0;
    if (t < EE) {
        float acc = 0.f;
        #pragma unroll
        for (int c = 0; c < 8; ++c)
            acc += vpart[(bh * 8 + c) * EE + t];
        vmean[bh * EE + t] = acc * (1.0f / TT);
    }
    __syncthreads();
    float mv = sM[t];
    int rank = 0;
    for (int i = 0; i < TT; ++i) {
        float o = sM[i];
        rank += (o > mv) || (o == mv && i < t);
    }
    if (rank < U) Mtop[bh * 64 + rank] = t;
}

// Fused flash-chunked attention + vmean broadcast fill.
// Blocks 0..255: attn partials (bh*8+ch). Blocks 256..767: fill out with vmean.
// No race: attn writes Opart/ml only; combine (next kernel) overwrites the
// selected rows of out afterwards.
__global__ __launch_bounds__(256)
void attn_fill(const float* __restrict__ q, const float* __restrict__ k,
               const float* __restrict__ v, const int* __restrict__ Mtop,
               const float* __restrict__ vmean, float* __restrict__ out,
               float* __restrict__ Opart, float* __restrict__ ml, int U) {
    __shared__ float qs[UPAD * 130];
    __shared__ float Bs[CH * 132];
    __shared__ float S[UPAD * 68];

    if (blockIdx.x >= 256) {
        int fb = blockIdx.x - 256;
        size_t i0 = (size_t)fb * 256 + threadIdx.x;
        #pragma unroll
        for (int r = 0; r < 8; ++r) {
            size_t tid4 = (i0 + (size_t)r * 131072) << 2;
            int d = tid4 & 63;
            size_t rest = tid4 >> 6;
            int h = rest & 7;  rest >>= 3;
            int nn = rest & 3; rest >>= 2;
            int b = (int)(rest >> 9);
            int e = (nn << 6) + d;
            int bh = (b << 3) + h;
            float4 val = *(const float4*)(vmean + (size_t)bh * EE + e);
            *(float4*)(out + tid4) = val;
        }
        return;
    }

    int bx = blockIdx.x;
    int bh = bx >> 3, ch = bx & 7;
    int b = bh >> 3, h = bh & 7;
    int tid = threadIdx.x;
    int wv = tid >> 6, l = tid & 63;

    float acc[4][4];
    #pragma unroll
    for (int i = 0; i < 4; ++i)
        #pragma unroll
        for (int j = 0; j < 4; ++j) acc[i][j] = 0.f;

    for (int h2 = 0; h2 < 2; ++h2) {
        int eb = h2 * 128;
        for (int u = wv; u < UPAD; u += 4) {
            int uu = (u < U) ? u : (U - 1);
            int qt = Mtop[bh * 64 + uu] & (TT - 1);
            size_t rowq = ((size_t)(b * TT + qt)) * ROWS;
            #pragma unroll
            for (int j = 0; j < 2; ++j) {
                int e = eb + l + 64 * j;
                qs[u * 130 + l + 64 * j] = q[rowq + (size_t)((e >> 6) * HH + h) * DD + (e & 63)];
            }
        }
        for (int r = wv; r < CH; r += 4) {
            size_t rowk = ((size_t)(b * TT + ch * CH + r)) * ROWS;
            #pragma unroll
            for (int j = 0; j < 2; ++j) {
                int e = eb + l + 64 * j;
                Bs[r * 129 + l + 64 * j] = k[rowk + (size_t)((e >> 6) * HH + h) * DD + (e & 63)];
            }
        }
        __syncthreads();
        if (tid < 144) {
            int ug = tid >> 4, tg = tid & 15;
            int u0 = ug << 2, t0 = tg << 2;
            for (int e = 0; e < 128; ++e) {
                float kx0 = Bs[(t0 + 0) * 129 + e];
                float kx1 = Bs[(t0 + 1) * 129 + e];
                float kx2 = Bs[(t0 + 2) * 129 + e];
                float kx3 = Bs[(t0 + 3) * 129 + e];
                #pragma unroll
                for (int i = 0; i < 4; ++i) {
                    float qv = qs[(u0 + i) * 130 + e];
                    acc[i][0] += qv * kx0;
                    acc[i][1] += qv * kx1;
                    acc[i][2] += qv * kx2;
                    acc[i][3] += qv * kx3;
                }
            }
        }
        __syncthreads();
    }
    if (tid < 144) {
        int ug = tid >> 4, tg = tid & 15;
        int u0 = ug << 2, t0 = tg << 2;
        #pragma unroll
        for (int i = 0; i < 4; ++i)
            #pragma unroll
            for (int j = 0; j < 4; ++j)
                S[(u0 + i) * 68 + t0 + j] = acc[i][j] * 0.125f;
    }
    __syncthreads();

    if (tid < UPAD) {
        float m = -3.4e38f;
        for (int t = 0; t < CH; ++t) m = fmaxf(m, S[tid * 68 + t]);
        float lsum = 0.f;
        for (int t = 0; t < CH; ++t) {
            float p = __expf(S[tid * 68 + t] - m);
            S[tid * 68 + t] = p;
            lsum += p;
        }
        size_t mli = ((size_t)(bh * NCH + ch) * UPAD + tid) * 2;
        ml[mli] = m;
        ml[mli + 1] = lsum;
    }
    __syncthreads();

    int ugp = tid >> 5, el = tid & 31;
    int u0p = ugp * 5;
    for (int vh = 0; vh < 2; ++vh) {
        for (int r = wv; r < CH; r += 4) {
            size_t rowv = ((size_t)(b * TT + ch * CH + r)) * ROWS;
            #pragma unroll
            for (int j = 0; j < 2; ++j) {
                int e = vh * 128 + l + 64 * j;
                Bs[r * 132 + l + 64 * j] = v[rowv + (size_t)((e >> 6) * HH + h) * DD + (e & 63)];
            }
        }
        __syncthreads();
        float4 o[5];
        #pragma unroll
        for (int i = 0; i < 5; ++i) o[i] = make_float4(0.f, 0.f, 0.f, 0.f);
        for (int t = 0; t < CH; ++t) {
            float4 v4 = *(const float4*)&Bs[t * 132 + 4 * el];
            #pragma unroll
            for (int i = 0; i < 5; ++i) {
                int uc = u0p + i; if (uc > 35) uc = 35;
                float p = S[uc * 68 + t];
                o[i].x += p * v4.x; o[i].y += p * v4.y;
                o[i].z += p * v4.z; o[i].w += p * v4.w;
            }
        }
        #pragma unroll
        for (int i = 0; i < 5; ++i) {
            int u = u0p + i;
            if (u < UPAD)
                *(float4*)&Opart[((size_t)(bh * NCH + ch) * UPAD + u) * EE + vh * 128 + 4 * el] = o[i];
        }
        __syncthreads();
    }
}

// merge chunk partials, write selected rows into out. Grid: 32*U x 64.
__global__ void combine_kernel(const float* __restrict__ Opart,
                               const float* __restrict__ ml,
                               const int* __restrict__ Mtop,
                               float* __restrict__ out, int U) {
    int bx = blockIdx.x;
    int bh = bx / U, ui = bx % U;
    int b = bh >> 3, h = bh & 7;
    int el = threadIdx.x;
    float mc[NCH], lc[NCH];
    float gm = -3.4e38f;
    #pragma unroll
    for (int c = 0; c < NCH; ++c) {
        size_t mli = ((size_t)(bh * NCH + c) * UPAD + ui) * 2;
        mc[c] = ml[mli]; lc[c] = ml[mli + 1];
        gm = fmaxf(gm, mc[c]);
    }
    float L = 0.f;
    float fc[NCH];
    #pragma unroll
    for (int c = 0; c < NCH; ++c) { fc[c] = __expf(mc[c] - gm); L += lc[c] * fc[c]; }
    float inv = 1.0f / L;
    float4 a = make_float4(0.f, 0.f, 0.f, 0.f);
    #pragma unroll
    for (int c = 0; c < NCH; ++c) {
        float4 o = *(const float4*)&Opart[((size_t)(bh * NCH + c) * UPAD + ui) * EE + 4 * el];
        a.x += fc[c] * o.x; a.y += fc[c] * o.y;
        a.z += fc[c] * o.z; a.w += fc[c] * o.w;
    }
    int qt = Mtop[bh * 64 + ui] & (TT - 1);
    int e0 = 4 * el, n = el >> 4;
    size_t ooff = ((size_t)(b * TT + qt)) * ROWS + (size_t)(n * HH + h) * DD + (e0 & 63);
    a.x *= inv; a.y *= inv; a.z *= inv; a.w *= inv;
    *(float4*)(out + ooff) = a;
}

// ---------------- mid-path kernels (ws >= 160 KB only) ----------------

__global__ __launch_bounds__(1024)
void vmean_kernel(const float* __restrict__ v, float* __restrict__ vmean) {
    __shared__ float part[4][EE];
    int bh = blockIdx.x;
    int b = bh >> 3, h = bh & 7;
    int e = threadIdx.x & 255;
    int chunk = threadIdx.x >> 8;
    int n = e >> 6, d = e & 63;
    size_t base = (size_t)b * TT * ROWS + (size_t)(n * HH + h) * DD + d;
    float acc = 0.f;
    int t0 = chunk * 128;
    for (int t = t0; t < t0 + 128; ++t)
        acc += v[base + (size_t)t * ROWS];
    part[chunk][e] = acc;
    __syncthreads();
    if (threadIdx.x < EE)
        vmean[bh * EE + threadIdx.x] =
            (part[0][threadIdx.x] + part[1][threadIdx.x] +
             part[2][threadIdx.x] + part[3][threadIdx.x]) * (1.0f / TT);
}

__global__ void fill_kernel(const float* __restrict__ vmean,
                            float* __restrict__ out) {
    size_t tid4 = ((size_t)blockIdx.x * 256 + threadIdx.x) << 2;
    int d = tid4 & 63;
    size_t rest = tid4 >> 6;
    int h = rest & 7;  rest >>= 3;
    int n = rest & 3;  rest >>= 2;
    int b = (int)(rest >> 9);
    int e = (n << 6) + d;
    int bh = (b << 3) + h;
    float4 val = *(const float4*)(vmean + (size_t)bh * EE + e);
    *(float4*)(out + tid4) = val;
}

__global__ void m_only_kernel(const float* __restrict__ q,
                              const float* __restrict__ k,
                              const int* __restrict__ idx,
                              float* __restrict__ M, int U) {
    int wave = threadIdx.x >> 6, lane = threadIdx.x & 63;
    int r = (blockIdx.x << 2) + wave;
    int t = r & (TT - 1);
    int bh = r >> 9;
    int b = bh >> 3, h = bh & 7;
    int g = lane >> 4, x = lane & 15;
    int n = x >> 2;
    int dbase = (x & 3) << 4;
    size_t colbase = (size_t)(n * HH + h) * DD + dbase;
    size_t qrow = ((size_t)(b * TT + t)) * ROWS + colbase;
    float4 qv0 = *(const float4*)(q + qrow);
    float4 qv1 = *(const float4*)(q + qrow + 4);
    float4 qv2 = *(const float4*)(q + qrow + 8);
    float4 qv3 = *(const float4*)(q + qrow + 12);
    float mx = -3.4e38f, sm = 0.f;
    int NB = (U + 3) >> 2;
    for (int bs = 0; bs < NB; ++bs) {
        int s = (bs << 2) + g;
        int valid = s < U;
        int sc = valid ? s : (U - 1);
        int kt = idx[t * U + sc] & (TT - 1);
        size_t krow = ((size_t)(b * TT + kt)) * ROWS + colbase;
        float4 kv0 = *(const float4*)(k + krow);
        float4 kv1 = *(const float4*)(k + krow + 4);
        float4 kv2 = *(const float4*)(k + krow + 8);
        float4 kv3 = *(const float4*)(k + krow + 12);
        float dot = qv0.x * kv0.x + qv0.y * kv0.y + qv0.z * kv0.z + qv0.w * kv0.w
                  + qv1.x * kv1.x + qv1.y * kv1.y + qv1.z * kv1.z + qv1.w * kv1.w
                  + qv2.x * kv2.x + qv2.y * kv2.y + qv2.z * kv2.z + qv2.w * kv2.w
                  + qv3.x * kv3.x + qv3.y * kv3.y + qv3.z * kv3.z + qv3.w * kv3.w;
        #pragma unroll
        for (int off = 1; off < 16; off <<= 1)
            dot += __shfl_xor(dot, off, 64);
        if (valid) { mx = fmaxf(mx, dot); sm += dot; }
    }
    mx = fmaxf(mx, __shfl_xor(mx, 16, 64));
    mx = fmaxf(mx, __shfl_xor(mx, 32, 64));
    sm += __shfl_xor(sm, 16, 64);
    sm += __shfl_xor(sm, 32, 64);
    if (lane == 0) M[r] = mx - sm * (1.0f / TT);
}

__global__ void topk_only_kernel(const float* __restrict__ M,
                                 int* __restrict__ Mtop, int U) {
    __shared__ float sM[TT];
    int bh = blockIdx.x;
    int t = threadIdx.x;
    sM[t] = M[bh * TT + t];
    if (t < 64) Mtop[bh * 64 + t] = 0;
    __syncthreads();
    float mv = sM[t];
    int rank = 0;
    for (int i = 0; i < TT; ++i) {
        float o = sM[i];
        rank += (o > mv) || (o == mv && i < t);
    }
    if (rank < U) Mtop[bh * 64 + rank] = t;
}

__global__ void update_kernel(const float* __restrict__ q,
                              const float* __restrict__ k,
                              const float* __restrict__ v,
                              const int* __restrict__ Mtop,
                              float* __restrict__ out, int U) {
    __shared__ float qs[EE];
    __shared__ float sc[TT];
    __shared__ float red[256];
    int blk = blockIdx.x;
    int ui = blk % U;
    int bh = blk / U;
    int b = bh >> 3, h = bh & 7;
    int tid = threadIdx.x;
    int qt = Mtop[bh * 64 + ui] & (TT - 1);
    {
        int n = tid >> 6, d = tid & 63;
        qs[tid] = q[((size_t)(b * TT + qt)) * ROWS + (size_t)(n * HH + h) * DD + d];
    }
    __syncthreads();
    #pragma unroll
    for (int rep = 0; rep < 2; ++rep) {
        int t = tid + rep * 256;
        size_t kb = ((size_t)(b * TT + t)) * ROWS + (size_t)h * DD;
        float acc = 0.f;
        #pragma unroll
        for (int n = 0; n < NN; ++n) {
            const float* kn = k + kb + (size_t)n * HH * DD;
            #pragma unroll 4
            for (int d4 = 0; d4 < DD; d4 += 4) {
                float4 kv = *(const float4*)(kn + d4);
                int e = n * 64 + d4;
                acc += qs[e] * kv.x + qs[e + 1] * kv.y + qs[e + 2] * kv.z + qs[e + 3] * kv.w;
            }
        }
        sc[t] = acc * 0.125f;
    }
    __syncthreads();
    red[tid] = fmaxf(sc[tid], sc[tid + 256]);
    __syncthreads();
    for (int s = 128; s > 0; s >>= 1) {
        if (tid < s) red[tid] = fmaxf(red[tid], red[tid + s]);
        __syncthreads();
    }
    float mx = red[0];
    __syncthreads();
    float e0 = __expf(sc[tid] - mx);
    float e1 = __expf(sc[tid + 256] - mx);
    sc[tid] = e0; sc[tid + 256] = e1;
    red[tid] = e0 + e1;
    __syncthreads();
    for (int s = 128; s > 0; s >>= 1) {
        if (tid < s) red[tid] += red[tid + s];
        __syncthreads();
    }
    float inv = 1.0f / red[0];
    __syncthreads();
    {
        int n = tid >> 6, d = tid & 63;
        size_t vb = (size_t)b * TT * ROWS + (size_t)(n * HH + h) * DD + d;
        float acc = 0.f;
        for (int t = 0; t < TT; ++t)
            acc += sc[t] * v[vb + (size_t)t * ROWS];
        out[((size_t)(b * TT + qt)) * ROWS + (size_t)(n * HH + h) * DD + d] = acc * inv;
    }
}

// ---------------- last-resort fallback (no ws): fused, fp32 ----------------
__global__ __launch_bounds__(1024)
void fused_probattn(const float* __restrict__ qp, const float* __restrict__ kp,
                    const float* __restrict__ vp, const int* __restrict__ idx,
                    float* __restrict__ out, int U) {
    __shared__ float vmean[EE];
    __shared__ float M[TT];
    __shared__ float sc[TT];
    __shared__ float qs[EE];
    __shared__ float red[64];
    __shared__ int   Mtop[64];
    const int bh = blockIdx.x;
    const int b = bh >> 3, h = bh & 7;
    const int tid = threadIdx.x;
    const int wave = tid >> 6, lane = tid & 63;
    if (tid < EE) {
        int n = tid >> 6, d = tid & 63;
        size_t base = (size_t)b * TT * ROWS + (size_t)(n * HH + h) * DD + d;
        float acc = 0.f;
        for (int t = 0; t < TT; ++t) acc += vp[base + (size_t)t * ROWS];
        vmean[tid] = acc * (1.0f / TT);
    }
    __syncthreads();
    for (int i = tid; i < TT * EE; i += 1024) {
        int t = i >> 8, e = i & 255;
        int n = e >> 6, d = e & 63;
        out[((size_t)(b * TT + t)) * ROWS + (size_t)(n * HH + h) * DD + d] = vmean[e];
    }
    {
        int e = lane << 2;
        int n = e >> 6, d = e & 63;
        size_t ebase = (size_t)(n * HH + h) * DD + d;
        for (int t = wave; t < TT; t += 16) {
            float4 qv = *(const float4*)(qp + ((size_t)(b * TT + t)) * ROWS + ebase);
            float mx = -3.4e38f, sm = 0.f;
            for (int s = 0; s < U; ++s) {
                int kt = idx[t * U + s] & (TT - 1);
                float4 kv = *(const float4*)(kp + ((size_t)(b * TT + kt)) * ROWS + ebase);
                float dot = qv.x * kv.x + qv.y * kv.y + qv.z * kv.z + qv.w * kv.w;
                #pragma unroll
                for (int off = 32; off; off >>= 1) dot += __shfl_xor(dot, off, 64);
                mx = fmaxf(mx, dot);
                sm += dot;
            }
            if (lane == 0) M[t] = mx - sm * (1.0f / TT);
        }
    }
    __syncthreads();
    if (tid < 64) Mtop[tid] = 0;
    __syncthreads();
    if (tid < TT) {
        float mv = M[tid];
        int rank = 0;
        for (int i = 0; i < TT; ++i) {
            float o = M[i];
            rank += (o > mv) || (o == mv && i < tid);
        }
        if (rank < U) Mtop[rank] = tid;
    }
    __syncthreads();
    for (int ui = 0; ui < U; ++ui) {
        int qt = Mtop[ui];
        if (tid < EE) {
            int n = tid >> 6, d = tid & 63;
            qs[tid] = qp[((size_t)(b * TT + qt)) * ROWS + (size_t)(n * HH + h) * DD + d];
        }
        __syncthreads();
        if (tid < TT) {
            float acc = 0.f;
            size_t kb = ((size_t)(b * TT + tid)) * ROWS + (size_t)h * DD;
            for (int n = 0; n < NN; ++n) {
                const float* kn = kp + kb + (size_t)n * HH * DD;
                for (int d = 0; d < DD; ++d) acc += qs[n * 64 + d] * kn[d];
            }
            sc[tid] = acc * 0.125f;
        }
        __syncthreads();
        float val = (tid < TT) ? sc[tid] : -3.4e38f;
        #pragma unroll
        for (int off = 32; off; off >>= 1) val = fmaxf(val, __shfl_xor(val, off, 64));
        if (lane == 0) red[wave] = val;
        __syncthreads();
        if (tid == 0) {
            float m = red[0];
            for (int w = 1; w < 16; ++w) m = fmaxf(m, red[w]);
            red[32] = m;
        }
        __syncthreads();
        float mx = red[32];
        float ev = 0.f;
        if (tid < TT) { ev = __expf(sc[tid] - mx); sc[tid] = ev; }
        __syncthreads();
        float sv = ev;
        #pragma unroll
        for (int off = 32; off; off >>= 1) sv += __shfl_xor(sv, off, 64);
        if (lane == 0) red[wave] = sv;
        __syncthreads();
        if (tid == 0) {
            float s = 0.f;
            for (int w = 0; w < 16; ++w) s += red[w];
            red[32] = s;
        }
        __syncthreads();
        float inv = 1.0f / red[32];
        if (tid < EE) {
            int n = tid >> 6, d = tid & 63;
            size_t vb = (size_t)b * TT * ROWS + (size_t)(n * HH + h) * DD + d;
            float acc = 0.f;
            for (int t = 0; t < TT; ++t) acc += sc[t] * vp[vb + (size_t)t * ROWS];
            out[((size_t)(b * TT + qt)) * ROWS + (size_t)(n * HH + h) * DD + d] = acc * inv;
        }
        __syncthreads();
    }
}

extern "C" void kernel_launch(void* const* d_in, const int* in_sizes, int n_in,
                              void* d_out, int out_size, void* d_ws, size_t ws_size,
                              hipStream_t stream) {
    const float* q = (const float*)d_in[0];
    const float* k = (const float*)d_in[1];
    const float* v = (const float*)d_in[2];
    const int* idx = (const int*)d_in[3];
    float* out = (float*)d_out;
    int U = in_sizes[3] / TT;        // 35

    // ws layout (bytes):
    //   M      @ 0        (64 KB)
    //   Mtop   @ 65536    (8 KB)
    //   vmean  @ 98304    (32 KB)
    //   ml     @ 131072   (73.7 KB)  [flash only]
    //   Opart  @ 204800   (9.44 MB)  [flash only]
    //   vpart  @ 204800   (256 KB)   [flash only; aliases Opart — disjoint lifetime]
    const size_t NEED_FLASH = 204800 + (size_t)32 * NCH * UPAD * EE * 4 + 1024;
    const size_t NEED_MID = 160 * 1024;
    char* ws = (char*)d_ws;
    float* M     = (float*)(ws);
    int*   Mtop  = (int*)  (ws + 65536);
    float* vmean = (float*)(ws + 98304);
    float* ml    = (float*)(ws + 131072);
    float* Opart = (float*)(ws + 204800);
    float* vpart = (float*)(ws + 204800);

    if (ws_size >= NEED_FLASH && U == 35) {
        m_vmean_kernel<<<4096 + 256, 256, 0, stream>>>(q, k, v, idx, M, vpart, U);
        topk_kernel<<<BB * HH, TT, 0, stream>>>(M, Mtop, vpart, vmean, U);
        attn_fill<<<256 + 512, 256, 0, stream>>>(q, k, v, Mtop, vmean, out, Opart, ml, U);
        combine_kernel<<<BB * HH * U, 64, 0, stream>>>(Opart, ml, Mtop, out, U);
    } else if (ws_size >= NEED_MID) {
        vmean_kernel<<<BB * HH, 1024, 0, stream>>>(v, vmean);
        fill_kernel<<<4096, 256, 0, stream>>>(vmean, out);
        m_only_kernel<<<BB * HH * TT / 4, 256, 0, stream>>>(q, k, idx, M, U);
        topk_only_kernel<<<BB * HH, TT, 0, stream>>>(M, Mtop, U);
        update_kernel<<<BB * HH * U, 256, 0, stream>>>(q, k, v, Mtop, out, U);
    } else {
        fused_probattn<<<BB * HH, 1024, 0, stream>>>(q, k, v, idx, out, U);
    }
}

// Round 8
// 171.607 us; speedup vs baseline: 26.5633x; 1.0868x over previous
//
#include <hip/hip_runtime.h>
#include <stdint.h>

#define BB 4
#define TT 512
#define NN 4      // heads-inner
#define HH 8      // H
#define DD 64     // D
#define EE 256    // N*D
#define ROWS 2048 // NN*HH*DD floats per (b,t)
#define UPAD 36   // padded u-count (U=35)
#define USAMP 35  // compile-time sample count (flash path gated on U==35)
#define NCH 8     // K/V chunks
#define CH 64     // rows per chunk

// ---------------- flash-path kernels ----------------

// Fused M-score + vmean partials.
// Blocks 0..2047: one (b,t) per block; all 8 h computed together from the
//   contiguous 2048-float K rows (one coalesced stream per sample, no per-h
//   gather, no loop-carried dependency -> deep vmcnt pipelining).
//   XCD affinity: b = (blockIdx&7)>>1 pins each XCD to one 4 MB K slice.
// Blocks 2048..2303: vmean partials (bh*8+chunk).
__global__ __launch_bounds__(256)
void m2_kernel(const float* __restrict__ q, const float* __restrict__ k,
               const float* __restrict__ v, const int* __restrict__ idx,
               float* __restrict__ M, float* __restrict__ vpart) {
    if (blockIdx.x >= 2048) {
        int blk = blockIdx.x - 2048;
        int chunk = blk & 7, bh = blk >> 3;
        int b = bh >> 3, h = bh & 7;
        int e = threadIdx.x;
        int n = e >> 6, d = e & 63;
        size_t base = (size_t)b * TT * ROWS + (size_t)(n * HH + h) * DD + d;
        float acc = 0.f;
        int t0 = chunk * 64;
        for (int t = t0; t < t0 + 64; ++t)
            acc += v[base + (size_t)t * ROWS];
        vpart[blk * EE + e] = acc;
        return;
    }
    __shared__ float S[USAMP][33];   // [sample][wave*8+h], padded stride 33
    __shared__ float Dh[8][36];      // [h][sample]
    int i = blockIdx.x;
    int xcd = i & 7;
    int b = xcd >> 1;
    int t = ((i >> 3) << 1) | (xcd & 1);
    int tid = threadIdx.x;
    int wave = tid >> 6, l = tid & 63;
    int h = (tid >> 3) & 7;

    const float* qr = q + ((size_t)(b * TT + t)) * ROWS + tid * 8;
    float4 qa = *(const float4*)qr;
    float4 qb = *(const float4*)(qr + 4);

    const int* irow = idx + t * USAMP;
    #pragma unroll
    for (int s = 0; s < USAMP; ++s) {
        int kt = __builtin_amdgcn_readfirstlane(irow[s]) & (TT - 1);
        const float* kr = k + ((size_t)(b * TT + kt)) * ROWS + tid * 8;
        float4 ka = *(const float4*)kr;
        float4 kb = *(const float4*)(kr + 4);
        float p = qa.x * ka.x + qa.y * ka.y + qa.z * ka.z + qa.w * ka.w
                + qb.x * kb.x + qb.y * kb.y + qb.z * kb.z + qb.w * kb.w;
        p += __shfl_xor(p, 1, 64);
        p += __shfl_xor(p, 2, 64);
        p += __shfl_xor(p, 4, 64);
        if ((l & 7) == 0) S[s][wave * 8 + h] = p;
    }
    __syncthreads();
    for (int j = tid; j < 8 * USAMP; j += 256) {
        int hh = j / USAMP, s = j - hh * USAMP;
        Dh[hh][s] = S[s][hh] + S[s][8 + hh] + S[s][16 + hh] + S[s][24 + hh];
    }
    __syncthreads();
    if (tid < 8) {
        float mx = -3.4e38f, sm = 0.f;
        #pragma unroll
        for (int s = 0; s < USAMP; ++s) {
            float d = Dh[tid][s];
            mx = fmaxf(mx, d);
            sm += d;
        }
        M[(((b << 3) + tid) << 9) + t] = mx - sm * (1.0f / TT);
    }
}

// exact top-k via rank + fused vmean final reduce. Grid: 32 x 512.
__global__ void topk_kernel(const float* __restrict__ M,
                            int* __restrict__ Mtop,
                            const float* __restrict__ vpart,
                            float* __restrict__ vmean, int U) {
    __shared__ float sM[TT];
    int bh = blockIdx.x;
    int t = threadIdx.x;
    sM[t] = M[bh * TT + t];
    if (t < 64) Mtop[bh * 64 + t] = 0;
    if (t < EE) {
        float acc = 0.f;
        #pragma unroll
        for (int c = 0; c < 8; ++c)
            acc += vpart[(bh * 8 + c) * EE + t];
        vmean[bh * EE + t] = acc * (1.0f / TT);
    }
    __syncthreads();
    float mv = sM[t];
    int rank = 0;
    for (int i = 0; i < TT; ++i) {
        float o = sM[i];
        rank += (o > mv) || (o == mv && i < t);
    }
    if (rank < U) Mtop[bh * 64 + rank] = t;
}

// Fused flash-chunked attention + vmean broadcast fill.
// Blocks 0..255: attn partials (bh*8+ch). Blocks 256..767: fill out with vmean.
__global__ __launch_bounds__(256)
void attn_fill(const float* __restrict__ q, const float* __restrict__ k,
               const float* __restrict__ v, const int* __restrict__ Mtop,
               const float* __restrict__ vmean, float* __restrict__ out,
               float* __restrict__ Opart, float* __restrict__ ml, int U) {
    __shared__ float qs[UPAD * 132];
    __shared__ float Bs[CH * 132];
    __shared__ float S[UPAD * 68];

    if (blockIdx.x >= 256) {
        int fb = blockIdx.x - 256;
        size_t i0 = (size_t)fb * 256 + threadIdx.x;
        #pragma unroll
        for (int r = 0; r < 8; ++r) {
            size_t tid4 = (i0 + (size_t)r * 131072) << 2;
            int d = tid4 & 63;
            size_t rest = tid4 >> 6;
            int h = rest & 7;  rest >>= 3;
            int nn = rest & 3; rest >>= 2;
            int b = (int)(rest >> 9);
            int e = (nn << 6) + d;
            int bh = (b << 3) + h;
            float4 val = *(const float4*)(vmean + (size_t)bh * EE + e);
            *(float4*)(out + tid4) = val;
        }
        return;
    }

    int bx = blockIdx.x;
    int bh = bx >> 3, ch = bx & 7;
    int b = bh >> 3, h = bh & 7;
    int tid = threadIdx.x;
    int wv = tid >> 6, l = tid & 63;

    float acc[4][4];
    #pragma unroll
    for (int i = 0; i < 4; ++i)
        #pragma unroll
        for (int j = 0; j < 4; ++j) acc[i][j] = 0.f;

    for (int h2 = 0; h2 < 2; ++h2) {
        int eb = h2 * 128;
        for (int u = wv; u < UPAD; u += 4) {
            int uu = (u < U) ? u : (U - 1);
            int qt = Mtop[bh * 64 + uu] & (TT - 1);
            size_t rowq = ((size_t)(b * TT + qt)) * ROWS;
            #pragma unroll
            for (int j = 0; j < 2; ++j) {
                int e = eb + l + 64 * j;
                qs[u * 132 + l + 64 * j] = q[rowq + (size_t)((e >> 6) * HH + h) * DD + (e & 63)];
            }
        }
        for (int r = wv; r < CH; r += 4) {
            size_t rowk = ((size_t)(b * TT + ch * CH + r)) * ROWS;
            #pragma unroll
            for (int j = 0; j < 2; ++j) {
                int e = eb + l + 64 * j;
                Bs[r * 132 + l + 64 * j] = k[rowk + (size_t)((e >> 6) * HH + h) * DD + (e & 63)];
            }
        }
        __syncthreads();
        if (tid < 144) {
            int ug = tid >> 4, tg = tid & 15;
            int u0 = ug << 2, t0 = tg << 2;
            const float4* Qv = (const float4*)qs;
            const float4* Bv = (const float4*)Bs;
            for (int e4 = 0; e4 < 32; ++e4) {
                float4 k0 = Bv[(t0 + 0) * 33 + e4];
                float4 k1 = Bv[(t0 + 1) * 33 + e4];
                float4 k2 = Bv[(t0 + 2) * 33 + e4];
                float4 k3 = Bv[(t0 + 3) * 33 + e4];
                #pragma unroll
                for (int i = 0; i < 4; ++i) {
                    float4 qv = Qv[(u0 + i) * 33 + e4];
                    acc[i][0] += qv.x * k0.x + qv.y * k0.y + qv.z * k0.z + qv.w * k0.w;
                    acc[i][1] += qv.x * k1.x + qv.y * k1.y + qv.z * k1.z + qv.w * k1.w;
                    acc[i][2] += qv.x * k2.x + qv.y * k2.y + qv.z * k2.z + qv.w * k2.w;
                    acc[i][3] += qv.x * k3.x + qv.y * k3.y + qv.z * k3.z + qv.w * k3.w;
                }
            }
        }
        __syncthreads();
    }
    if (tid < 144) {
        int ug = tid >> 4, tg = tid & 15;
        int u0 = ug << 2, t0 = tg << 2;
        #pragma unroll
        for (int i = 0; i < 4; ++i)
            #pragma unroll
            for (int j = 0; j < 4; ++j)
                S[(u0 + i) * 68 + t0 + j] = acc[i][j] * 0.125f;
    }
    __syncthreads();

    if (tid < UPAD) {
        float m = -3.4e38f;
        for (int t = 0; t < CH; ++t) m = fmaxf(m, S[tid * 68 + t]);
        float lsum = 0.f;
        for (int t = 0; t < CH; ++t) {
            float p = __expf(S[tid * 68 + t] - m);
            S[tid * 68 + t] = p;
            lsum += p;
        }
        size_t mli = ((size_t)(bh * NCH + ch) * UPAD + tid) * 2;
        ml[mli] = m;
        ml[mli + 1] = lsum;
    }
    __syncthreads();

    int ugp = tid >> 5, el = tid & 31;
    int u0p = ugp * 5;
    for (int vh = 0; vh < 2; ++vh) {
        for (int r = wv; r < CH; r += 4) {
            size_t rowv = ((size_t)(b * TT + ch * CH + r)) * ROWS;
            #pragma unroll
            for (int j = 0; j < 2; ++j) {
                int e = vh * 128 + l + 64 * j;
                Bs[r * 132 + l + 64 * j] = v[rowv + (size_t)((e >> 6) * HH + h) * DD + (e & 63)];
            }
        }
        __syncthreads();
        float4 o[5];
        #pragma unroll
        for (int i = 0; i < 5; ++i) o[i] = make_float4(0.f, 0.f, 0.f, 0.f);
        for (int t = 0; t < CH; ++t) {
            float4 v4 = *(const float4*)&Bs[t * 132 + 4 * el];
            #pragma unroll
            for (int i = 0; i < 5; ++i) {
                int uc = u0p + i; if (uc > 35) uc = 35;
                float p = S[uc * 68 + t];
                o[i].x += p * v4.x; o[i].y += p * v4.y;
                o[i].z += p * v4.z; o[i].w += p * v4.w;
            }
        }
        #pragma unroll
        for (int i = 0; i < 5; ++i) {
            int u = u0p + i;
            if (u < UPAD)
                *(float4*)&Opart[((size_t)(bh * NCH + ch) * UPAD + u) * EE + vh * 128 + 4 * el] = o[i];
        }
        __syncthreads();
    }
}

// merge chunk partials, write selected rows into out. Grid: 32*U x 64.
__global__ void combine_kernel(const float* __restrict__ Opart,
                               const float* __restrict__ ml,
                               const int* __restrict__ Mtop,
                               float* __restrict__ out, int U) {
    int bx = blockIdx.x;
    int bh = bx / U, ui = bx % U;
    int b = bh >> 3, h = bh & 7;
    int el = threadIdx.x;
    float mc[NCH], lc[NCH];
    float gm = -3.4e38f;
    #pragma unroll
    for (int c = 0; c < NCH; ++c) {
        size_t mli = ((size_t)(bh * NCH + c) * UPAD + ui) * 2;
        mc[c] = ml[mli]; lc[c] = ml[mli + 1];
        gm = fmaxf(gm, mc[c]);
    }
    float L = 0.f;
    float fc[NCH];
    #pragma unroll
    for (int c = 0; c < NCH; ++c) { fc[c] = __expf(mc[c] - gm); L += lc[c] * fc[c]; }
    float inv = 1.0f / L;
    float4 a = make_float4(0.f, 0.f, 0.f, 0.f);
    #pragma unroll
    for (int c = 0; c < NCH; ++c) {
        float4 o = *(const float4*)&Opart[((size_t)(bh * NCH + c) * UPAD + ui) * EE + 4 * el];
        a.x += fc[c] * o.x; a.y += fc[c] * o.y;
        a.z += fc[c] * o.z; a.w += fc[c] * o.w;
    }
    int qt = Mtop[bh * 64 + ui] & (TT - 1);
    int e0 = 4 * el, n = el >> 4;
    size_t ooff = ((size_t)(b * TT + qt)) * ROWS + (size_t)(n * HH + h) * DD + (e0 & 63);
    a.x *= inv; a.y *= inv; a.z *= inv; a.w *= inv;
    *(float4*)(out + ooff) = a;
}

// ---------------- mid-path kernels (ws >= 160 KB only) ----------------

__global__ __launch_bounds__(1024)
void vmean_kernel(const float* __restrict__ v, float* __restrict__ vmean) {
    __shared__ float part[4][EE];
    int bh = blockIdx.x;
    int b = bh >> 3, h = bh & 7;
    int e = threadIdx.x & 255;
    int chunk = threadIdx.x >> 8;
    int n = e >> 6, d = e & 63;
    size_t base = (size_t)b * TT * ROWS + (size_t)(n * HH + h) * DD + d;
    float acc = 0.f;
    int t0 = chunk * 128;
    for (int t = t0; t < t0 + 128; ++t)
        acc += v[base + (size_t)t * ROWS];
    part[chunk][e] = acc;
    __syncthreads();
    if (threadIdx.x < EE)
        vmean[bh * EE + threadIdx.x] =
            (part[0][threadIdx.x] + part[1][threadIdx.x] +
             part[2][threadIdx.x] + part[3][threadIdx.x]) * (1.0f / TT);
}

__global__ void fill_kernel(const float* __restrict__ vmean,
                            float* __restrict__ out) {
    size_t tid4 = ((size_t)blockIdx.x * 256 + threadIdx.x) << 2;
    int d = tid4 & 63;
    size_t rest = tid4 >> 6;
    int h = rest & 7;  rest >>= 3;
    int n = rest & 3;  rest >>= 2;
    int b = (int)(rest >> 9);
    int e = (n << 6) + d;
    int bh = (b << 3) + h;
    float4 val = *(const float4*)(vmean + (size_t)bh * EE + e);
    *(float4*)(out + tid4) = val;
}

__global__ void m_only_kernel(const float* __restrict__ q,
                              const float* __restrict__ k,
                              const int* __restrict__ idx,
                              float* __restrict__ M, int U) {
    int wave = threadIdx.x >> 6, lane = threadIdx.x & 63;
    int r = (blockIdx.x << 2) + wave;
    int t = r & (TT - 1);
    int bh = r >> 9;
    int b = bh >> 3, h = bh & 7;
    int g = lane >> 4, x = lane & 15;
    int n = x >> 2;
    int dbase = (x & 3) << 4;
    size_t colbase = (size_t)(n * HH + h) * DD + dbase;
    size_t qrow = ((size_t)(b * TT + t)) * ROWS + colbase;
    float4 qv0 = *(const float4*)(q + qrow);
    float4 qv1 = *(const float4*)(q + qrow + 4);
    float4 qv2 = *(const float4*)(q + qrow + 8);
    float4 qv3 = *(const float4*)(q + qrow + 12);
    float mx = -3.4e38f, sm = 0.f;
    int NB = (U + 3) >> 2;
    for (int bs = 0; bs < NB; ++bs) {
        int s = (bs << 2) + g;
        int valid = s < U;
        int sc = valid ? s : (U - 1);
        int kt = idx[t * U + sc] & (TT - 1);
        size_t krow = ((size_t)(b * TT + kt)) * ROWS + colbase;
        float4 kv0 = *(const float4*)(k + krow);
        float4 kv1 = *(const float4*)(k + krow + 4);
        float4 kv2 = *(const float4*)(k + krow + 8);
        float4 kv3 = *(const float4*)(k + krow + 12);
        float dot = qv0.x * kv0.x + qv0.y * kv0.y + qv0.z * kv0.z + qv0.w * kv0.w
                  + qv1.x * kv1.x + qv1.y * kv1.y + qv1.z * kv1.z + qv1.w * kv1.w
                  + qv2.x * kv2.x + qv2.y * kv2.y + qv2.z * kv2.z + qv2.w * kv2.w
                  + qv3.x * kv3.x + qv3.y * kv3.y + qv3.z * kv3.z + qv3.w * kv3.w;
        #pragma unroll
        for (int off = 1; off < 16; off <<= 1)
            dot += __shfl_xor(dot, off, 64);
        if (valid) { mx = fmaxf(mx, dot); sm += dot; }
    }
    mx = fmaxf(mx, __shfl_xor(mx, 16, 64));
    mx = fmaxf(mx, __shfl_xor(mx, 32, 64));
    sm += __shfl_xor(sm, 16, 64);
    sm += __shfl_xor(sm, 32, 64);
    if (lane == 0) M[r] = mx - sm * (1.0f / TT);
}

__global__ void topk_only_kernel(const float* __restrict__ M,
                                 int* __restrict__ Mtop, int U) {
    __shared__ float sM[TT];
    int bh = blockIdx.x;
    int t = threadIdx.x;
    sM[t] = M[bh * TT + t];
    if (t < 64) Mtop[bh * 64 + t] = 0;
    __syncthreads();
    float mv = sM[t];
    int rank = 0;
    for (int i = 0; i < TT; ++i) {
        float o = sM[i];
        rank += (o > mv) || (o == mv && i < t);
    }
    if (rank < U) Mtop[bh * 64 + rank] = t;
}

__global__ void update_kernel(const float* __restrict__ q,
                              const float* __restrict__ k,
                              const float* __restrict__ v,
                              const int* __restrict__ Mtop,
                              float* __restrict__ out, int U) {
    __shared__ float qs[EE];
    __shared__ float sc[TT];
    __shared__ float red[256];
    int blk = blockIdx.x;
    int ui = blk % U;
    int bh = blk / U;
    int b = bh >> 3, h = bh & 7;
    int tid = threadIdx.x;
    int qt = Mtop[bh * 64 + ui] & (TT - 1);
    {
        int n = tid >> 6, d = tid & 63;
        qs[tid] = q[((size_t)(b * TT + qt)) * ROWS + (size_t)(n * HH + h) * DD + d];
    }
    __syncthreads();
    #pragma unroll
    for (int rep = 0; rep < 2; ++rep) {
        int t = tid + rep * 256;
        size_t kb = ((size_t)(b * TT + t)) * ROWS + (size_t)h * DD;
        float acc = 0.f;
        #pragma unroll
        for (int n = 0; n < NN; ++n) {
            const float* kn = k + kb + (size_t)n * HH * DD;
            #pragma unroll 4
            for (int d4 = 0; d4 < DD; d4 += 4) {
                float4 kv = *(const float4*)(kn + d4);
                int e = n * 64 + d4;
                acc += qs[e] * kv.x + qs[e + 1] * kv.y + qs[e + 2] * kv.z + qs[e + 3] * kv.w;
            }
        }
        sc[t] = acc * 0.125f;
    }
    __syncthreads();
    red[tid] = fmaxf(sc[tid], sc[tid + 256]);
    __syncthreads();
    for (int s = 128; s > 0; s >>= 1) {
        if (tid < s) red[tid] = fmaxf(red[tid], red[tid + s]);
        __syncthreads();
    }
    float mx = red[0];
    __syncthreads();
    float e0 = __expf(sc[tid] - mx);
    float e1 = __expf(sc[tid + 256] - mx);
    sc[tid] = e0; sc[tid + 256] = e1;
    red[tid] = e0 + e1;
    __syncthreads();
    for (int s = 128; s > 0; s >>= 1) {
        if (tid < s) red[tid] += red[tid + s];
        __syncthreads();
    }
    float inv = 1.0f / red[0];
    __syncthreads();
    {
        int n = tid >> 6, d = tid & 63;
        size_t vb = (size_t)b * TT * ROWS + (size_t)(n * HH + h) * DD + d;
        float acc = 0.f;
        for (int t = 0; t < TT; ++t)
            acc += sc[t] * v[vb + (size_t)t * ROWS];
        out[((size_t)(b * TT + qt)) * ROWS + (size_t)(n * HH + h) * DD + d] = acc * inv;
    }
}

// ---------------- last-resort fallback (no ws): fused, fp32 ----------------
__global__ __launch_bounds__(1024)
void fused_probattn(const float* __restrict__ qp, const float* __restrict__ kp,
                    const float* __restrict__ vp, const int* __restrict__ idx,
                    float* __restrict__ out, int U) {
    __shared__ float vmean[EE];
    __shared__ float M[TT];
    __shared__ float sc[TT];
    __shared__ float qs[EE];
    __shared__ float red[64];
    __shared__ int   Mtop[64];
    const int bh = blockIdx.x;
    const int b = bh >> 3, h = bh & 7;
    const int tid = threadIdx.x;
    const int wave = tid >> 6, lane = tid & 63;
    if (tid < EE) {
        int n = tid >> 6, d = tid & 63;
        size_t base = (size_t)b * TT * ROWS + (size_t)(n * HH + h) * DD + d;
        float acc = 0.f;
        for (int t = 0; t < TT; ++t) acc += vp[base + (size_t)t * ROWS];
        vmean[tid] = acc * (1.0f / TT);
    }
    __syncthreads();
    for (int i = tid; i < TT * EE; i += 1024) {
        int t = i >> 8, e = i & 255;
        int n = e >> 6, d = e & 63;
        out[((size_t)(b * TT + t)) * ROWS + (size_t)(n * HH + h) * DD + d] = vmean[e];
    }
    {
        int e = lane << 2;
        int n = e >> 6, d = e & 63;
        size_t ebase = (size_t)(n * HH + h) * DD + d;
        for (int t = wave; t < TT; t += 16) {
            float4 qv = *(const float4*)(qp + ((size_t)(b * TT + t)) * ROWS + ebase);
            float mx = -3.4e38f, sm = 0.f;
            for (int s = 0; s < U; ++s) {
                int kt = idx[t * U + s] & (TT - 1);
                float4 kv = *(const float4*)(kp + ((size_t)(b * TT + kt)) * ROWS + ebase);
                float dot = qv.x * kv.x + qv.y * kv.y + qv.z * kv.z + qv.w * kv.w;
                #pragma unroll
                for (int off = 32; off; off >>= 1) dot += __shfl_xor(dot, off, 64);
                mx = fmaxf(mx, dot);
                sm += dot;
            }
            if (lane == 0) M[t] = mx - sm * (1.0f / TT);
        }
    }
    __syncthreads();
    if (tid < 64) Mtop[tid] = 0;
    __syncthreads();
    if (tid < TT) {
        float mv = M[tid];
        int rank = 0;
        for (int i = 0; i < TT; ++i) {
            float o = M[i];
            rank += (o > mv) || (o == mv && i < tid);
        }
        if (rank < U) Mtop[rank] = tid;
    }
    __syncthreads();
    for (int ui = 0; ui < U; ++ui) {
        int qt = Mtop[ui];
        if (tid < EE) {
            int n = tid >> 6, d = tid & 63;
            qs[tid] = qp[((size_t)(b * TT + qt)) * ROWS + (size_t)(n * HH + h) * DD + d];
        }
        __syncthreads();
        if (tid < TT) {
            float acc = 0.f;
            size_t kb = ((size_t)(b * TT + tid)) * ROWS + (size_t)h * DD;
            for (int n = 0; n < NN; ++n) {
                const float* kn = kp + kb + (size_t)n * HH * DD;
                for (int d = 0; d < DD; ++d) acc += qs[n * 64 + d] * kn[d];
            }
            sc[tid] = acc * 0.125f;
        }
        __syncthreads();
        float val = (tid < TT) ? sc[tid] : -3.4e38f;
        #pragma unroll
        for (int off = 32; off; off >>= 1) val = fmaxf(val, __shfl_xor(val, off, 64));
        if (lane == 0) red[wave] = val;
        __syncthreads();
        if (tid == 0) {
            float m = red[0];
            for (int w = 1; w < 16; ++w) m = fmaxf(m, red[w]);
            red[32] = m;
        }
        __syncthreads();
        float mx = red[32];
        float ev = 0.f;
        if (tid < TT) { ev = __expf(sc[tid] - mx); sc[tid] = ev; }
        __syncthreads();
        float sv = ev;
        #pragma unroll
        for (int off = 32; off; off >>= 1) sv += __shfl_xor(sv, off, 64);
        if (lane == 0) red[wave] = sv;
        __syncthreads();
        if (tid == 0) {
            float s = 0.f;
            for (int w = 0; w < 16; ++w) s += red[w];
            red[32] = s;
        }
        __syncthreads();
        float inv = 1.0f / red[32];
        if (tid < EE) {
            int n = tid >> 6, d = tid & 63;
            size_t vb = (size_t)b * TT * ROWS + (size_t)(n * HH + h) * DD + d;
            float acc = 0.f;
            for (int t = 0; t < TT; ++t) acc += sc[t] * vp[vb + (size_t)t * ROWS];
            out[((size_t)(b * TT + qt)) * ROWS + (size_t)(n * HH + h) * DD + d] = acc * inv;
        }
        __syncthreads();
    }
}

extern "C" void kernel_launch(void* const* d_in, const int* in_sizes, int n_in,
                              void* d_out, int out_size, void* d_ws, size_t ws_size,
                              hipStream_t stream) {
    const float* q = (const float*)d_in[0];
    const float* k = (const float*)d_in[1];
    const float* v = (const float*)d_in[2];
    const int* idx = (const int*)d_in[3];
    float* out = (float*)d_out;
    int U = in_sizes[3] / TT;        // 35

    // ws layout (bytes):
    //   M      @ 0        (64 KB)
    //   Mtop   @ 65536    (8 KB)
    //   vmean  @ 98304    (32 KB)
    //   ml     @ 131072   (73.7 KB)  [flash only]
    //   Opart  @ 204800   (9.44 MB)  [flash only]
    //   vpart  @ 204800   (256 KB)   [flash only; aliases Opart — disjoint lifetime]
    const size_t NEED_FLASH = 204800 + (size_t)32 * NCH * UPAD * EE * 4 + 1024;
    const size_t NEED_MID = 160 * 1024;
    char* ws = (char*)d_ws;
    float* M     = (float*)(ws);
    int*   Mtop  = (int*)  (ws + 65536);
    float* vmean = (float*)(ws + 98304);
    float* ml    = (float*)(ws + 131072);
    float* Opart = (float*)(ws + 204800);
    float* vpart = (float*)(ws + 204800);

    if (ws_size >= NEED_FLASH && U == USAMP) {
        m2_kernel<<<2048 + 256, 256, 0, stream>>>(q, k, v, idx, M, vpart);
        topk_kernel<<<BB * HH, TT, 0, stream>>>(M, Mtop, vpart, vmean, U);
        attn_fill<<<256 + 512, 256, 0, stream>>>(q, k, v, Mtop, vmean, out, Opart, ml, U);
        combine_kernel<<<BB * HH * U, 64, 0, stream>>>(Opart, ml, Mtop, out, U);
    } else if (ws_size >= NEED_MID) {
        vmean_kernel<<<BB * HH, 1024, 0, stream>>>(v, vmean);
        fill_kernel<<<4096, 256, 0, stream>>>(vmean, out);
        m_only_kernel<<<BB * HH * TT / 4, 256, 0, stream>>>(q, k, idx, M, U);
        topk_only_kernel<<<BB * HH, TT, 0, stream>>>(M, Mtop, U);
        update_kernel<<<BB * HH * U, 256, 0, stream>>>(q, k, v, Mtop, out, U);
    } else {
        fused_probattn<<<BB * HH, 1024, 0, stream>>>(q, k, v, idx, out, U);
    }
}